// Round 1
// baseline (8252.238 us; speedup 1.0000x reference)
//
#include <hip/hip_runtime.h>
#include <math.h>

#define NN 100000
#define NE 3200000
#define NG 64
#define EPSF 1e-5f

// ---- workspace layout (float offsets) ----
#define OFF_AGG1   0          // 100000*16
#define OFF_AGG2   1600000    // 100000*32
#define OFF_CNT    4800000    // 100000
#define OFF_ST1    4900000    // 16 sum + 16 sumsq
#define OFF_ST2    4900032    // 32 sum + 32 sumsq
#define OFF_GPOOL  4900096    // 64*32
#define ZERO_FLOATS 4902144   // everything above gets memset to 0
#define OFF_H1     4902144    // 100000*16
#define OFF_H2     6502144    // 100000*32
#define OFF_STARTS 9702144    // 65 ints (reinterpreted)

__device__ __forceinline__ void atomAdd(float* p, float v) {
#if defined(__gfx90a__) || defined(__gfx940__) || defined(__gfx941__) || defined(__gfx942__) || defined(__gfx950__)
    unsafeAtomicAdd(p, v);
#else
    atomicAdd(p, v);
#endif
}

__device__ __forceinline__ float eluf(float x) { return x > 0.f ? x : expm1f(x); }

// ---- per-graph node starts via binary search over sorted batch ----
__global__ void starts_k(const int* __restrict__ batch, int* __restrict__ starts) {
    int g = threadIdx.x;
    if (g > NG) return;
    int lo = 0, hi = NN;
    while (lo < hi) { int mid = (lo + hi) >> 1; if (batch[mid] < g) lo = mid + 1; else hi = mid; }
    starts[g] = lo;
}

// ---- conv1: per-edge message + scatter (16 ch) ----
__global__ void conv1_edge(const int* __restrict__ ei, const float* __restrict__ ea,
                           const float* __restrict__ x, const float* __restrict__ W1,
                           float* __restrict__ agg1, float* __restrict__ cnt) {
    int e = blockIdx.x * blockDim.x + threadIdx.x;
    if (e >= NE) return;
    int src = ei[e];
    int dst = ei[NE + e];
    float p0 = ea[2 * e], p1 = ea[2 * e + 1];
    float b0 = (1.f - p1) * (1.f - p0);
    float b1 = (1.f - p1) * p0;
    float b2 = p1 * (1.f - p0);
    float b3 = p1 * p0;
    float bb[4] = {b0, b1, b2, b3};
    float x0 = x[3 * src], x1 = x[3 * src + 1], x2 = x[3 * src + 2];
    float* out = agg1 + (long)dst * 16;
#pragma unroll
    for (int o = 0; o < 16; ++o) {
        float m = 0.f;
#pragma unroll
        for (int k = 0; k < 4; ++k) {
            float t = fmaf(W1[k * 48 + o], x0,
                      fmaf(W1[k * 48 + 16 + o], x1,
                           W1[k * 48 + 32 + o] * x2));
            m = fmaf(bb[k], t, m);
        }
        atomAdd(out + o, m);
    }
    atomAdd(cnt + dst, 1.0f);
}

// ---- bn stats + elu + store pre-normalized h (16 ch) ----
__global__ void bn_stats16(const float* __restrict__ agg, const float* __restrict__ cnt,
                           float* __restrict__ hpre, float* __restrict__ st) {
    __shared__ float s_sum[16], s_sq[16];
    if (threadIdx.x < 16) { s_sum[threadIdx.x] = 0.f; s_sq[threadIdx.x] = 0.f; }
    __syncthreads();
    const int total = NN * 16;
    const int stride = gridDim.x * blockDim.x;  // multiple of 16
    float acc = 0.f, accq = 0.f;
    for (int idx = blockIdx.x * blockDim.x + threadIdx.x; idx < total; idx += stride) {
        int node = idx >> 4;
        float v = agg[idx] / fmaxf(cnt[node], 1.f);
        v = eluf(v);
        hpre[idx] = v;
        acc += v;
        accq += v * v;
    }
    acc  += __shfl_xor(acc, 16);  acc  += __shfl_xor(acc, 32);
    accq += __shfl_xor(accq, 16); accq += __shfl_xor(accq, 32);
    int lane = threadIdx.x & 63;
    if (lane < 16) { atomicAdd(&s_sum[lane], acc); atomicAdd(&s_sq[lane], accq); }
    __syncthreads();
    if (threadIdx.x < 16) {
        atomAdd(&st[threadIdx.x], s_sum[threadIdx.x]);
        atomAdd(&st[16 + threadIdx.x], s_sq[threadIdx.x]);
    }
}

// ---- conv2: per-edge, BN1 affine applied on gathered h1, direct msg (32 ch) ----
__global__ void conv2_edge(const int* __restrict__ ei, const float* __restrict__ ea,
                           const float* __restrict__ h1pre, const float* __restrict__ st1,
                           const float* __restrict__ g1, const float* __restrict__ b1v,
                           const float* __restrict__ W2, float* __restrict__ agg2) {
    __shared__ float sc[16], sh[16];
    if (threadIdx.x < 16) {
        int c = threadIdx.x;
        float mu = st1[c] * (1.f / NN);
        float var = st1[16 + c] * (1.f / NN) - mu * mu;
        float rs = rsqrtf(var + EPSF);
        float s = g1[c] * rs;
        sc[c] = s;
        sh[c] = b1v[c] - mu * s;
    }
    __syncthreads();
    int e = blockIdx.x * blockDim.x + threadIdx.x;
    if (e >= NE) return;
    int src = ei[e];
    int dst = ei[NE + e];
    float p0 = ea[2 * e], p1 = ea[2 * e + 1];
    float bb[4] = {(1.f - p1) * (1.f - p0), (1.f - p1) * p0, p1 * (1.f - p0), p1 * p0};
    float h[16];
    const float4* hp = (const float4*)(h1pre + (long)src * 16);
#pragma unroll
    for (int q = 0; q < 4; ++q) {
        float4 v = hp[q];
        h[4 * q + 0] = fmaf(v.x, sc[4 * q + 0], sh[4 * q + 0]);
        h[4 * q + 1] = fmaf(v.y, sc[4 * q + 1], sh[4 * q + 1]);
        h[4 * q + 2] = fmaf(v.z, sc[4 * q + 2], sh[4 * q + 2]);
        h[4 * q + 3] = fmaf(v.w, sc[4 * q + 3], sh[4 * q + 3]);
    }
    float msg[32];
#pragma unroll
    for (int o = 0; o < 32; ++o) msg[o] = 0.f;
#pragma unroll
    for (int k = 0; k < 4; ++k) {
#pragma unroll
        for (int i = 0; i < 16; ++i) {
            float g = bb[k] * h[i];
            const float* w = W2 + k * 512 + i * 32;
#pragma unroll
            for (int o = 0; o < 32; ++o) msg[o] = fmaf(g, w[o], msg[o]);
        }
    }
    float* out = agg2 + (long)dst * 32;
#pragma unroll
    for (int o = 0; o < 32; ++o) atomAdd(out + o, msg[o]);
}

// ---- bn stats + elu + store pre-normalized h (32 ch) ----
__global__ void bn_stats32(const float* __restrict__ agg, const float* __restrict__ cnt,
                           float* __restrict__ hpre, float* __restrict__ st) {
    __shared__ float s_sum[32], s_sq[32];
    if (threadIdx.x < 32) { s_sum[threadIdx.x] = 0.f; s_sq[threadIdx.x] = 0.f; }
    __syncthreads();
    const int total = NN * 32;
    const int stride = gridDim.x * blockDim.x;  // multiple of 32
    float acc = 0.f, accq = 0.f;
    for (int idx = blockIdx.x * blockDim.x + threadIdx.x; idx < total; idx += stride) {
        int node = idx >> 5;
        float v = agg[idx] / fmaxf(cnt[node], 1.f);
        v = eluf(v);
        hpre[idx] = v;
        acc += v;
        accq += v * v;
    }
    acc  += __shfl_xor(acc, 32);
    accq += __shfl_xor(accq, 32);
    int lane = threadIdx.x & 63;
    if (lane < 32) { atomicAdd(&s_sum[lane], acc); atomicAdd(&s_sq[lane], accq); }
    __syncthreads();
    if (threadIdx.x < 32) {
        atomAdd(&st[threadIdx.x], s_sum[threadIdx.x]);
        atomAdd(&st[32 + threadIdx.x], s_sq[threadIdx.x]);
    }
}

// ---- per-graph mean pool with BN2 affine, exploiting sorted batch ----
__global__ void pool_k(const float* __restrict__ h2pre, const float* __restrict__ st2,
                       const float* __restrict__ g2, const float* __restrict__ b2v,
                       const int* __restrict__ batch, float* __restrict__ gpool) {
    int t = blockIdx.x * blockDim.x + threadIdx.x;
    int c = t & 31;
    int chunk = t >> 5;
    if (chunk >= NN / 32) return;  // 3125 chunks of 32 nodes
    float mu = st2[c] * (1.f / NN);
    float var = st2[32 + c] * (1.f / NN) - mu * mu;
    float rs = rsqrtf(var + EPSF);
    float s = g2[c] * rs;
    float sh = b2v[c] - mu * s;
    int n0 = chunk * 32;
    int g_cur = batch[n0];
    float acc = 0.f;
    for (int i = 0; i < 32; ++i) {
        int n = n0 + i;
        int g = batch[n];
        float v = fmaf(h2pre[(long)n * 32 + c], s, sh);
        if (g != g_cur) {
            atomAdd(gpool + g_cur * 32 + c, acc);
            acc = 0.f;
            g_cur = g;
        }
        acc += v;
    }
    atomAdd(gpool + g_cur * 32 + c, acc);
}

// ---- final: gm = gpool/cnt ; out = gm @ fc^T ----
__global__ void final_k(const float* __restrict__ gpool, const int* __restrict__ starts,
                        const float* __restrict__ fc, float* __restrict__ out) {
    int t = blockIdx.x * blockDim.x + threadIdx.x;
    if (t >= NG * 10) return;
    int g = t / 10, j = t - g * 10;
    float cg = (float)(starts[g + 1] - starts[g]);
    float inv = 1.f / fmaxf(cg, 1.f);
    float sv = 0.f;
#pragma unroll
    for (int ch = 0; ch < 32; ++ch) sv = fmaf(gpool[g * 32 + ch], fc[j * 32 + ch], sv);
    out[t] = sv * inv;
}

extern "C" void kernel_launch(void* const* d_in, const int* in_sizes, int n_in,
                              void* d_out, int out_size, void* d_ws, size_t ws_size,
                              hipStream_t stream) {
    const float* x    = (const float*)d_in[0];
    const int*   ei   = (const int*)d_in[1];
    const float* ea   = (const float*)d_in[2];
    const int*   batch= (const int*)d_in[3];
    const float* W1   = (const float*)d_in[4];
    const float* g1   = (const float*)d_in[5];
    const float* b1v  = (const float*)d_in[6];
    const float* W2   = (const float*)d_in[7];
    const float* g2   = (const float*)d_in[8];
    const float* b2v  = (const float*)d_in[9];
    const float* fc   = (const float*)d_in[10];
    float* ws = (float*)d_ws;

    float* agg1  = ws + OFF_AGG1;
    float* agg2  = ws + OFF_AGG2;
    float* cnt   = ws + OFF_CNT;
    float* st1   = ws + OFF_ST1;
    float* st2   = ws + OFF_ST2;
    float* gpool = ws + OFF_GPOOL;
    float* h1    = ws + OFF_H1;
    float* h2    = ws + OFF_H2;
    int*   starts= (int*)(ws + OFF_STARTS);

    hipMemsetAsync(ws, 0, (size_t)ZERO_FLOATS * sizeof(float), stream);
    starts_k<<<1, 128, 0, stream>>>(batch, starts);

    const int BLK = 256;
    conv1_edge<<<(NE + BLK - 1) / BLK, BLK, 0, stream>>>(ei, ea, x, W1, agg1, cnt);
    bn_stats16<<<512, BLK, 0, stream>>>(agg1, cnt, h1, st1);
    conv2_edge<<<(NE + BLK - 1) / BLK, BLK, 0, stream>>>(ei, ea, h1, st1, g1, b1v, W2, agg2);
    bn_stats32<<<512, BLK, 0, stream>>>(agg2, cnt, h2, st2);
    pool_k<<<(NN + BLK - 1) / BLK, BLK, 0, stream>>>(h2, st2, g2, b2v, batch, gpool);
    final_k<<<3, BLK, 0, stream>>>(gpool, starts, fc, (float*)d_out);
}

// Round 2
// 961.070 us; speedup vs baseline: 8.5865x; 8.5865x over previous
//
#include <hip/hip_runtime.h>
#include <math.h>

#define NN 100000
#define NE 3200000
#define NG 64
#define EPSF 1e-5f

// ---- workspace layout (float offsets) ----
#define OFF_DEG     0          // int[100000]  (zeroed)
#define OFF_ST1     100000     // 16 sum + 16 sumsq (zeroed)
#define OFF_ST2     100032     // 32 sum + 32 sumsq (zeroed)
#define OFF_GPOOL   100096     // 64*32 (zeroed)
#define ZERO_FLOATS 102144
#define OFF_OFFS    102144     // int[100001]
#define OFF_CURSOR  202148     // int[100000]
#define OFF_CSRC    302148     // int[3200000]
#define OFF_CSRP    3502148    // float2[3200000] (16B aligned)
#define OFF_H1      9902148    // float[100000*16] (16B aligned)
#define OFF_H2      11502148   // float[100000*32] (16B aligned)
#define OFF_STARTS  14702148   // int[65]
// total 14702213 floats = 58.8 MB

__device__ __forceinline__ void atomAdd(float* p, float v) {
#if defined(__gfx90a__) || defined(__gfx940__) || defined(__gfx941__) || defined(__gfx942__) || defined(__gfx950__)
    unsafeAtomicAdd(p, v);
#else
    atomicAdd(p, v);
#endif
}

__device__ __forceinline__ float eluf(float x) { return x > 0.f ? x : expm1f(x); }

// ---- per-graph node starts via binary search over sorted batch ----
__global__ void starts_k(const int* __restrict__ batch, int* __restrict__ starts) {
    int g = threadIdx.x;
    if (g > NG) return;
    int lo = 0, hi = NN;
    while (lo < hi) { int mid = (lo + hi) >> 1; if (batch[mid] < g) lo = mid + 1; else hi = mid; }
    starts[g] = lo;
}

// ---- in-degree histogram (int atomics) ----
__global__ void deg_k(const int* __restrict__ ei, int* __restrict__ deg) {
    int e = blockIdx.x * blockDim.x + threadIdx.x;
    if (e < NE) atomicAdd(&deg[ei[NE + e]], 1);
}

// ---- single-block exclusive scan of deg -> offs, cursor ----
#define SCAN_T 1024
#define SCAN_CH 98  // 1024*98 >= 100000
__global__ void scan_k(const int* __restrict__ deg, int* __restrict__ offs,
                       int* __restrict__ cursor) {
    __shared__ int s[SCAN_T];
    int t = threadIdx.x;
    int lo = t * SCAN_CH, hi = min(lo + SCAN_CH, NN);
    int sum = 0;
    for (int i = lo; i < hi; ++i) sum += deg[i];
    s[t] = sum;
    __syncthreads();
    for (int d = 1; d < SCAN_T; d <<= 1) {
        int v = (t >= d) ? s[t - d] : 0;
        __syncthreads();
        s[t] += v;
        __syncthreads();
    }
    int run = s[t] - sum;  // exclusive prefix
    for (int i = lo; i < hi; ++i) { offs[i] = run; cursor[i] = run; run += deg[i]; }
    if (t == SCAN_T - 1) offs[NN] = s[SCAN_T - 1];
}

// ---- scatter edges into CSR order (int atomics only) ----
__global__ void scatter_k(const int* __restrict__ ei, const float* __restrict__ ea,
                          int* __restrict__ cursor, int* __restrict__ csr_src,
                          float2* __restrict__ csr_p) {
    int e = blockIdx.x * blockDim.x + threadIdx.x;
    if (e >= NE) return;
    int dst = ei[NE + e];
    int pos = atomicAdd(&cursor[dst], 1);
    csr_src[pos] = ei[e];
    const float2* ea2 = (const float2*)ea;
    csr_p[pos] = ea2[e];
}

// ---- conv1: gather per node, T[4][3] in regs, 12x16 GEMV ----
__global__ void __launch_bounds__(256) conv1_gather(const int* __restrict__ offs,
        const int* __restrict__ csr_src, const float2* __restrict__ csr_p,
        const float* __restrict__ x, const float* __restrict__ W1,
        float* __restrict__ h1) {
    __shared__ float sW[192];
    if (threadIdx.x < 192) sW[threadIdx.x] = W1[threadIdx.x];
    __syncthreads();
    int n = blockIdx.x * blockDim.x + threadIdx.x;
    if (n >= NN) return;
    int off = offs[n], end = offs[n + 1];
    float T[12];
#pragma unroll
    for (int i = 0; i < 12; ++i) T[i] = 0.f;
    for (int e = off; e < end; ++e) {
        int s = csr_src[e];
        float2 p = csr_p[e];
        float b0 = (1.f - p.y) * (1.f - p.x), b1 = (1.f - p.y) * p.x;
        float b2 = p.y * (1.f - p.x), b3 = p.y * p.x;
        float x0 = x[3 * s], x1 = x[3 * s + 1], x2 = x[3 * s + 2];
        T[0] = fmaf(b0, x0, T[0]);  T[1] = fmaf(b0, x1, T[1]);  T[2]  = fmaf(b0, x2, T[2]);
        T[3] = fmaf(b1, x0, T[3]);  T[4] = fmaf(b1, x1, T[4]);  T[5]  = fmaf(b1, x2, T[5]);
        T[6] = fmaf(b2, x0, T[6]);  T[7] = fmaf(b2, x1, T[7]);  T[8]  = fmaf(b2, x2, T[8]);
        T[9] = fmaf(b3, x0, T[9]);  T[10]= fmaf(b3, x1, T[10]); T[11] = fmaf(b3, x2, T[11]);
    }
    float inv = 1.f / fmaxf((float)(end - off), 1.f);
    float ov[16];
#pragma unroll
    for (int o = 0; o < 16; ++o) {
        float acc = 0.f;
#pragma unroll
        for (int k = 0; k < 4; ++k)
#pragma unroll
            for (int i = 0; i < 3; ++i)
                acc = fmaf(T[k * 3 + i], sW[k * 48 + i * 16 + o], acc);
        acc *= inv;
        ov[o] = eluf(acc);
    }
    float4* hp = (float4*)(h1 + (long)n * 16);
#pragma unroll
    for (int q = 0; q < 4; ++q)
        hp[q] = make_float4(ov[4 * q], ov[4 * q + 1], ov[4 * q + 2], ov[4 * q + 3]);
}

// ---- BN stats: plain sum/sumsq over h (C channels) ----
template <int C>
__global__ void bn_sum(const float* __restrict__ h, float* __restrict__ st) {
    __shared__ float ss[C], sq[C];
    if (threadIdx.x < C) { ss[threadIdx.x] = 0.f; sq[threadIdx.x] = 0.f; }
    __syncthreads();
    const int total = NN * C;
    const int stride = gridDim.x * blockDim.x;  // multiple of C
    float a = 0.f, q = 0.f;
    for (int i = blockIdx.x * blockDim.x + threadIdx.x; i < total; i += stride) {
        float v = h[i];
        a += v; q += v * v;
    }
#pragma unroll
    for (int d = C; d < 64; d <<= 1) { a += __shfl_xor(a, d); q += __shfl_xor(q, d); }
    int lane = threadIdx.x & 63;
    if (lane < C) { atomicAdd(&ss[lane], a); atomicAdd(&sq[lane], q); }
    __syncthreads();
    if (threadIdx.x < C) {
        atomAdd(&st[threadIdx.x], ss[threadIdx.x]);
        atomAdd(&st[C + threadIdx.x], sq[threadIdx.x]);
    }
}

// ---- conv2: gather per node, U[64]+S[4] in regs, 64x32 GEMV vs LDS W2' ----
__global__ void __launch_bounds__(256) conv2_gather(const int* __restrict__ offs,
        const int* __restrict__ csr_src, const float2* __restrict__ csr_p,
        const float* __restrict__ h1, const float* __restrict__ st1,
        const float* __restrict__ g1, const float* __restrict__ b1v,
        const float* __restrict__ W2, float* __restrict__ h2) {
    __shared__ float s_sc[16], s_sh[16];
    __shared__ float sWp[2048];  // sc_i * W2[k][i][o]
    __shared__ float sV[128];    // sum_i sh_i * W2[k][i][o]
    if (threadIdx.x < 16) {
        int c = threadIdx.x;
        float mu = st1[c] * (1.f / NN);
        float var = st1[16 + c] * (1.f / NN) - mu * mu;
        float rs = rsqrtf(var + EPSF);
        float s = g1[c] * rs;
        s_sc[c] = s;
        s_sh[c] = b1v[c] - mu * s;
    }
    __syncthreads();
    for (int idx = threadIdx.x; idx < 2048; idx += blockDim.x) {
        int i = (idx & 511) >> 5;
        sWp[idx] = s_sc[i] * W2[idx];
    }
    if (threadIdx.x < 128) {
        int k = threadIdx.x >> 5, o = threadIdx.x & 31;
        float acc = 0.f;
#pragma unroll
        for (int i = 0; i < 16; ++i) acc = fmaf(s_sh[i], W2[k * 512 + i * 32 + o], acc);
        sV[threadIdx.x] = acc;
    }
    __syncthreads();
    int n = blockIdx.x * blockDim.x + threadIdx.x;
    if (n >= NN) return;
    int off = offs[n], end = offs[n + 1];
    float U[64];
    float S0 = 0.f, S1 = 0.f, S2 = 0.f, S3 = 0.f;
#pragma unroll
    for (int i = 0; i < 64; ++i) U[i] = 0.f;
    for (int e = off; e < end; ++e) {
        int s = csr_src[e];
        float2 p = csr_p[e];
        float b0 = (1.f - p.y) * (1.f - p.x), b1 = (1.f - p.y) * p.x;
        float b2 = p.y * (1.f - p.x), b3 = p.y * p.x;
        const float4* hp = (const float4*)(h1 + (long)s * 16);
        float4 t0 = hp[0], t1 = hp[1], t2 = hp[2], t3 = hp[3];
        float hv[16] = {t0.x, t0.y, t0.z, t0.w, t1.x, t1.y, t1.z, t1.w,
                        t2.x, t2.y, t2.z, t2.w, t3.x, t3.y, t3.z, t3.w};
#pragma unroll
        for (int i = 0; i < 16; ++i) {
            U[i]      = fmaf(b0, hv[i], U[i]);
            U[16 + i] = fmaf(b1, hv[i], U[16 + i]);
            U[32 + i] = fmaf(b2, hv[i], U[32 + i]);
            U[48 + i] = fmaf(b3, hv[i], U[48 + i]);
        }
        S0 += b0; S1 += b1; S2 += b2; S3 += b3;
    }
    float inv = 1.f / fmaxf((float)(end - off), 1.f);
    float4 acc[8];
#pragma unroll
    for (int ob = 0; ob < 8; ++ob) acc[ob] = make_float4(0.f, 0.f, 0.f, 0.f);
    const float4* Wp4 = (const float4*)sWp;
#pragma unroll 4
    for (int ki = 0; ki < 64; ++ki) {
        float u = U[ki];
#pragma unroll
        for (int ob = 0; ob < 8; ++ob) {
            float4 w = Wp4[ki * 8 + ob];
            acc[ob].x = fmaf(u, w.x, acc[ob].x);
            acc[ob].y = fmaf(u, w.y, acc[ob].y);
            acc[ob].z = fmaf(u, w.z, acc[ob].z);
            acc[ob].w = fmaf(u, w.w, acc[ob].w);
        }
    }
    const float4* V4 = (const float4*)sV;
    float Sarr[4] = {S0, S1, S2, S3};
#pragma unroll
    for (int k = 0; k < 4; ++k) {
        float u = Sarr[k];
#pragma unroll
        for (int ob = 0; ob < 8; ++ob) {
            float4 w = V4[k * 8 + ob];
            acc[ob].x = fmaf(u, w.x, acc[ob].x);
            acc[ob].y = fmaf(u, w.y, acc[ob].y);
            acc[ob].z = fmaf(u, w.z, acc[ob].z);
            acc[ob].w = fmaf(u, w.w, acc[ob].w);
        }
    }
    float4* out4 = (float4*)(h2 + (long)n * 32);
#pragma unroll
    for (int ob = 0; ob < 8; ++ob) {
        float4 a = acc[ob];
        a.x = eluf(a.x * inv); a.y = eluf(a.y * inv);
        a.z = eluf(a.z * inv); a.w = eluf(a.w * inv);
        out4[ob] = a;
    }
}

// ---- per-graph mean pool with BN2 affine, exploiting sorted batch ----
__global__ void pool_k(const float* __restrict__ h2pre, const float* __restrict__ st2,
                       const float* __restrict__ g2, const float* __restrict__ b2v,
                       const int* __restrict__ batch, float* __restrict__ gpool) {
    int t = blockIdx.x * blockDim.x + threadIdx.x;
    int c = t & 31;
    int chunk = t >> 5;
    if (chunk >= NN / 32) return;
    float mu = st2[c] * (1.f / NN);
    float var = st2[32 + c] * (1.f / NN) - mu * mu;
    float rs = rsqrtf(var + EPSF);
    float s = g2[c] * rs;
    float sh = b2v[c] - mu * s;
    int n0 = chunk * 32;
    int g_cur = batch[n0];
    float acc = 0.f;
    for (int i = 0; i < 32; ++i) {
        int n = n0 + i;
        int g = batch[n];
        float v = fmaf(h2pre[(long)n * 32 + c], s, sh);
        if (g != g_cur) {
            atomAdd(gpool + g_cur * 32 + c, acc);
            acc = 0.f;
            g_cur = g;
        }
        acc += v;
    }
    atomAdd(gpool + g_cur * 32 + c, acc);
}

// ---- final: gm = gpool/cnt ; out = gm @ fc^T ----
__global__ void final_k(const float* __restrict__ gpool, const int* __restrict__ starts,
                        const float* __restrict__ fc, float* __restrict__ out) {
    int t = blockIdx.x * blockDim.x + threadIdx.x;
    if (t >= NG * 10) return;
    int g = t / 10, j = t - g * 10;
    float cg = (float)(starts[g + 1] - starts[g]);
    float inv = 1.f / fmaxf(cg, 1.f);
    float sv = 0.f;
#pragma unroll
    for (int ch = 0; ch < 32; ++ch) sv = fmaf(gpool[g * 32 + ch], fc[j * 32 + ch], sv);
    out[t] = sv * inv;
}

extern "C" void kernel_launch(void* const* d_in, const int* in_sizes, int n_in,
                              void* d_out, int out_size, void* d_ws, size_t ws_size,
                              hipStream_t stream) {
    const float* x     = (const float*)d_in[0];
    const int*   ei    = (const int*)d_in[1];
    const float* ea    = (const float*)d_in[2];
    const int*   batch = (const int*)d_in[3];
    const float* W1    = (const float*)d_in[4];
    const float* g1    = (const float*)d_in[5];
    const float* b1v   = (const float*)d_in[6];
    const float* W2    = (const float*)d_in[7];
    const float* g2    = (const float*)d_in[8];
    const float* b2v   = (const float*)d_in[9];
    const float* fc    = (const float*)d_in[10];
    float* ws = (float*)d_ws;

    int*    deg    = (int*)(ws + OFF_DEG);
    float*  st1    = ws + OFF_ST1;
    float*  st2    = ws + OFF_ST2;
    float*  gpool  = ws + OFF_GPOOL;
    int*    offs   = (int*)(ws + OFF_OFFS);
    int*    cursor = (int*)(ws + OFF_CURSOR);
    int*    csrc   = (int*)(ws + OFF_CSRC);
    float2* csrp   = (float2*)(ws + OFF_CSRP);
    float*  h1     = ws + OFF_H1;
    float*  h2     = ws + OFF_H2;
    int*    starts = (int*)(ws + OFF_STARTS);

    hipMemsetAsync(ws, 0, (size_t)ZERO_FLOATS * sizeof(float), stream);
    starts_k<<<1, 128, 0, stream>>>(batch, starts);

    const int BLK = 256;
    const int EGRID = (NE + BLK - 1) / BLK;
    const int NGRID = (NN + BLK - 1) / BLK;

    deg_k<<<EGRID, BLK, 0, stream>>>(ei, deg);
    scan_k<<<1, SCAN_T, 0, stream>>>(deg, offs, cursor);
    scatter_k<<<EGRID, BLK, 0, stream>>>(ei, ea, cursor, csrc, csrp);
    conv1_gather<<<NGRID, BLK, 0, stream>>>(offs, csrc, csrp, x, W1, h1);
    bn_sum<16><<<512, BLK, 0, stream>>>(h1, st1);
    conv2_gather<<<NGRID, BLK, 0, stream>>>(offs, csrc, csrp, h1, st1, g1, b1v, W2, h2);
    bn_sum<32><<<512, BLK, 0, stream>>>(h2, st2);
    pool_k<<<NGRID, BLK, 0, stream>>>(h2, st2, g2, b2v, batch, gpool);
    final_k<<<3, BLK, 0, stream>>>(gpool, starts, fc, (float*)d_out);
}

// Round 4
// 706.539 us; speedup vs baseline: 11.6798x; 1.3603x over previous
//
#include <hip/hip_runtime.h>
#include <math.h>

#define NN 100000
#define NE 3200000
#define NG 64
#define EPSF 1e-5f

// ---- workspace layout (float offsets), all float4-aligned where needed ----
#define OFF_OFFS    0          // int[100001] (+pad) -- deg accumulated here, scanned in place
#define OFF_ST1     100004     // 16 sum + 16 sumsq
#define OFF_ST2     100036     // 32 sum + 32 sumsq
#define OFF_GPOOL   100100     // 64*32
#define ZERO_FLOATS 102148     // everything above memset to 0
#define OFF_CURSOR  102148     // int[100000]
#define OFF_H1      202148     // float[100000*16]  (%4==0)
#define OFF_H2      1802148    // float[100000*32]  (%4==0)
#define OFF_RECS    5002148    // float4[3200000]   (%4==0)
#define OFF_STARTS  17802148   // int[65]
#define OFF_BOFF    17802216   // int[200]
// total ~17.81M floats = 71.3 MB

__device__ __forceinline__ void atomAdd(float* p, float v) {
#if defined(__gfx90a__) || defined(__gfx940__) || defined(__gfx941__) || defined(__gfx942__) || defined(__gfx950__)
    unsafeAtomicAdd(p, v);
#else
    atomicAdd(p, v);
#endif
}

__device__ __forceinline__ float eluf(float x) { return x > 0.f ? x : expm1f(x); }

// ---- per-graph node starts via binary search over sorted batch ----
__global__ void starts_k(const int* __restrict__ batch, int* __restrict__ starts) {
    int g = threadIdx.x;
    if (g > NG) return;
    int lo = 0, hi = NN;
    while (lo < hi) { int mid = (lo + hi) >> 1; if (batch[mid] < g) lo = mid + 1; else hi = mid; }
    starts[g] = lo;
}

// ---- in-degree histogram into offs (int atomics), 4 edges/thread ----
__global__ void deg_k(const int* __restrict__ ei, int* __restrict__ deg) {
    int t = blockIdx.x * blockDim.x + threadIdx.x;
    int base = t * 4;
    if (base >= NE) return;
    int4 d = *(const int4*)(ei + NE + base);
    atomicAdd(&deg[d.x], 1);
    atomicAdd(&deg[d.y], 1);
    atomicAdd(&deg[d.z], 1);
    atomicAdd(&deg[d.w], 1);
}

// ---- 3-phase multi-block exclusive scan of offs (in place) ----
#define SBLK 512
#define NSB  ((NN + SBLK - 1) / SBLK)   // 196
__global__ void scan_a(int* __restrict__ offs, int* __restrict__ bsum) {
    __shared__ int s[SBLK];
    int i = blockIdx.x * SBLK + threadIdx.x;
    int v = (i < NN) ? offs[i] : 0;
    s[threadIdx.x] = v;
    __syncthreads();
    for (int d = 1; d < SBLK; d <<= 1) {
        int t = (threadIdx.x >= (unsigned)d) ? s[threadIdx.x - d] : 0;
        __syncthreads();
        s[threadIdx.x] += t;
        __syncthreads();
    }
    if (i < NN) offs[i] = s[threadIdx.x] - v;   // exclusive within block
    if (threadIdx.x == SBLK - 1) bsum[blockIdx.x] = s[SBLK - 1];
}
__global__ void scan_b(int* __restrict__ bsum) {
    __shared__ int s[256];
    int v = (threadIdx.x < NSB) ? bsum[threadIdx.x] : 0;
    s[threadIdx.x] = v;
    __syncthreads();
    for (int d = 1; d < 256; d <<= 1) {
        int t = (threadIdx.x >= (unsigned)d) ? s[threadIdx.x - d] : 0;
        __syncthreads();
        s[threadIdx.x] += t;
        __syncthreads();
    }
    if (threadIdx.x < NSB) bsum[threadIdx.x] = s[threadIdx.x] - v;  // exclusive
}
__global__ void scan_c(int* __restrict__ offs, const int* __restrict__ bsum,
                       int* __restrict__ cursor) {
    int i = blockIdx.x * blockDim.x + threadIdx.x;
    if (i < NN) {
        int o = offs[i] + bsum[i / SBLK];
        offs[i] = o;
        cursor[i] = o;
    }
    if (i == 0) offs[NN] = NE;
}

// ---- scatter edges into CSR order: one 16B record per edge ----
__global__ void scatter_k(const int* __restrict__ ei, const float* __restrict__ ea,
                          int* __restrict__ cursor, float4* __restrict__ recs) {
    int e = blockIdx.x * blockDim.x + threadIdx.x;
    if (e >= NE) return;
    int dst = ei[NE + e];
    int pos = atomicAdd(&cursor[dst], 1);
    float2 p = ((const float2*)ea)[e];
    float4 r;
    r.x = __int_as_float(ei[e]);
    r.y = p.x;
    r.z = p.y;
    r.w = 0.f;
    recs[pos] = r;
}

// ---- conv1: gather per node, T[4][3] in regs, 12x16 GEMV ----
__global__ void __launch_bounds__(256) conv1_gather(const int* __restrict__ offs,
        const float4* __restrict__ recs, const float* __restrict__ x,
        const float* __restrict__ W1, float* __restrict__ h1) {
    __shared__ float sW[192];
    if (threadIdx.x < 192) sW[threadIdx.x] = W1[threadIdx.x];
    __syncthreads();
    int n = blockIdx.x * blockDim.x + threadIdx.x;
    if (n >= NN) return;
    int off = offs[n], end = offs[n + 1];
    float T[12];
#pragma unroll
    for (int i = 0; i < 12; ++i) T[i] = 0.f;
    for (int e = off; e < end; ++e) {
        float4 r = recs[e];
        int s = __float_as_int(r.x);
        float p0 = r.y, p1 = r.z;
        float b0 = (1.f - p1) * (1.f - p0), b1 = (1.f - p1) * p0;
        float b2 = p1 * (1.f - p0), b3 = p1 * p0;
        float x0 = x[3 * s], x1 = x[3 * s + 1], x2 = x[3 * s + 2];
        T[0] = fmaf(b0, x0, T[0]);  T[1] = fmaf(b0, x1, T[1]);  T[2]  = fmaf(b0, x2, T[2]);
        T[3] = fmaf(b1, x0, T[3]);  T[4] = fmaf(b1, x1, T[4]);  T[5]  = fmaf(b1, x2, T[5]);
        T[6] = fmaf(b2, x0, T[6]);  T[7] = fmaf(b2, x1, T[7]);  T[8]  = fmaf(b2, x2, T[8]);
        T[9] = fmaf(b3, x0, T[9]);  T[10]= fmaf(b3, x1, T[10]); T[11] = fmaf(b3, x2, T[11]);
    }
    float inv = 1.f / fmaxf((float)(end - off), 1.f);
    float ov[16];
#pragma unroll
    for (int o = 0; o < 16; ++o) {
        float acc = 0.f;
#pragma unroll
        for (int k = 0; k < 4; ++k)
#pragma unroll
            for (int i = 0; i < 3; ++i)
                acc = fmaf(T[k * 3 + i], sW[k * 48 + i * 16 + o], acc);
        acc *= inv;
        ov[o] = eluf(acc);
    }
    float4* hp = (float4*)(h1 + (long)n * 16);
#pragma unroll
    for (int q = 0; q < 4; ++q)
        hp[q] = make_float4(ov[4 * q], ov[4 * q + 1], ov[4 * q + 2], ov[4 * q + 3]);
}

// ---- BN stats: plain sum/sumsq over h (C channels) ----
template <int C>
__global__ void bn_sum(const float* __restrict__ h, float* __restrict__ st) {
    __shared__ float ss[C], sq[C];
    if (threadIdx.x < C) { ss[threadIdx.x] = 0.f; sq[threadIdx.x] = 0.f; }
    __syncthreads();
    const int total = NN * C;
    const int stride = gridDim.x * blockDim.x;
    float a = 0.f, q = 0.f;
    for (int i = blockIdx.x * blockDim.x + threadIdx.x; i < total; i += stride) {
        float v = h[i];
        a += v; q += v * v;
    }
#pragma unroll
    for (int d = C; d < 64; d <<= 1) { a += __shfl_xor(a, d); q += __shfl_xor(q, d); }
    int lane = threadIdx.x & 63;
    if (lane < C) { atomicAdd(&ss[lane], a); atomicAdd(&sq[lane], q); }
    __syncthreads();
    if (threadIdx.x < C) {
        atomAdd(&st[threadIdx.x], ss[threadIdx.x]);
        atomAdd(&st[C + threadIdx.x], sq[threadIdx.x]);
    }
}

// ---- conv2: gather per node, U[64]+S[4] in regs, 64x32 GEMV vs LDS W2' ----
__global__ void __launch_bounds__(256) conv2_gather(const int* __restrict__ offs,
        const float4* __restrict__ recs, const float* __restrict__ h1,
        const float* __restrict__ st1, const float* __restrict__ g1,
        const float* __restrict__ b1v, const float* __restrict__ W2,
        float* __restrict__ h2) {
    __shared__ float s_sc[16], s_sh[16];
    __shared__ float sWp[2048];  // sc_i * W2[k][i][o]
    __shared__ float sV[128];    // sum_i sh_i * W2[k][i][o]
    if (threadIdx.x < 16) {
        int c = threadIdx.x;
        float mu = st1[c] * (1.f / NN);
        float var = st1[16 + c] * (1.f / NN) - mu * mu;
        float rs = rsqrtf(var + EPSF);
        float s = g1[c] * rs;
        s_sc[c] = s;
        s_sh[c] = b1v[c] - mu * s;
    }
    __syncthreads();
    for (int idx = threadIdx.x; idx < 2048; idx += blockDim.x) {
        int i = (idx & 511) >> 5;
        sWp[idx] = s_sc[i] * W2[idx];
    }
    if (threadIdx.x < 128) {
        int k = threadIdx.x >> 5, o = threadIdx.x & 31;
        float acc = 0.f;
#pragma unroll
        for (int i = 0; i < 16; ++i) acc = fmaf(s_sh[i], W2[k * 512 + i * 32 + o], acc);
        sV[threadIdx.x] = acc;
    }
    __syncthreads();
    int n = blockIdx.x * blockDim.x + threadIdx.x;
    if (n >= NN) return;
    int off = offs[n], end = offs[n + 1];
    float U[64];
    float S0 = 0.f, S1 = 0.f, S2 = 0.f, S3 = 0.f;
#pragma unroll
    for (int i = 0; i < 64; ++i) U[i] = 0.f;
    for (int e = off; e < end; ++e) {
        float4 r = recs[e];
        int s = __float_as_int(r.x);
        float p0 = r.y, p1 = r.z;
        float b0 = (1.f - p1) * (1.f - p0), b1 = (1.f - p1) * p0;
        float b2 = p1 * (1.f - p0), b3 = p1 * p0;
        const float4* hp = (const float4*)(h1 + (long)s * 16);
        float4 t0 = hp[0], t1 = hp[1], t2 = hp[2], t3 = hp[3];
        float hv[16] = {t0.x, t0.y, t0.z, t0.w, t1.x, t1.y, t1.z, t1.w,
                        t2.x, t2.y, t2.z, t2.w, t3.x, t3.y, t3.z, t3.w};
#pragma unroll
        for (int i = 0; i < 16; ++i) {
            U[i]      = fmaf(b0, hv[i], U[i]);
            U[16 + i] = fmaf(b1, hv[i], U[16 + i]);
            U[32 + i] = fmaf(b2, hv[i], U[32 + i]);
            U[48 + i] = fmaf(b3, hv[i], U[48 + i]);
        }
        S0 += b0; S1 += b1; S2 += b2; S3 += b3;
    }
    float inv = 1.f / fmaxf((float)(end - off), 1.f);
    float4 acc[8];
#pragma unroll
    for (int ob = 0; ob < 8; ++ob) acc[ob] = make_float4(0.f, 0.f, 0.f, 0.f);
    const float4* Wp4 = (const float4*)sWp;
#pragma unroll 4
    for (int ki = 0; ki < 64; ++ki) {
        float u = U[ki];
#pragma unroll
        for (int ob = 0; ob < 8; ++ob) {
            float4 w = Wp4[ki * 8 + ob];
            acc[ob].x = fmaf(u, w.x, acc[ob].x);
            acc[ob].y = fmaf(u, w.y, acc[ob].y);
            acc[ob].z = fmaf(u, w.z, acc[ob].z);
            acc[ob].w = fmaf(u, w.w, acc[ob].w);
        }
    }
    const float4* V4 = (const float4*)sV;
    float Sarr[4] = {S0, S1, S2, S3};
#pragma unroll
    for (int k = 0; k < 4; ++k) {
        float u = Sarr[k];
#pragma unroll
        for (int ob = 0; ob < 8; ++ob) {
            float4 w = V4[k * 8 + ob];
            acc[ob].x = fmaf(u, w.x, acc[ob].x);
            acc[ob].y = fmaf(u, w.y, acc[ob].y);
            acc[ob].z = fmaf(u, w.z, acc[ob].z);
            acc[ob].w = fmaf(u, w.w, acc[ob].w);
        }
    }
    float4* out4 = (float4*)(h2 + (long)n * 32);
#pragma unroll
    for (int ob = 0; ob < 8; ++ob) {
        float4 a = acc[ob];
        a.x = eluf(a.x * inv); a.y = eluf(a.y * inv);
        a.z = eluf(a.z * inv); a.w = eluf(a.w * inv);
        out4[ob] = a;
    }
}

// ---- per-graph mean pool with BN2 affine, exploiting sorted batch ----
__global__ void pool_k(const float* __restrict__ h2pre, const float* __restrict__ st2,
                       const float* __restrict__ g2, const float* __restrict__ b2v,
                       const int* __restrict__ batch, float* __restrict__ gpool) {
    int t = blockIdx.x * blockDim.x + threadIdx.x;
    int c = t & 31;
    int chunk = t >> 5;
    if (chunk >= NN / 32) return;
    float mu = st2[c] * (1.f / NN);
    float var = st2[32 + c] * (1.f / NN) - mu * mu;
    float rs = rsqrtf(var + EPSF);
    float s = g2[c] * rs;
    float sh = b2v[c] - mu * s;
    int n0 = chunk * 32;
    int g_cur = batch[n0];
    float acc = 0.f;
    for (int i = 0; i < 32; ++i) {
        int n = n0 + i;
        int g = batch[n];
        float v = fmaf(h2pre[(long)n * 32 + c], s, sh);
        if (g != g_cur) {
            atomAdd(gpool + g_cur * 32 + c, acc);
            acc = 0.f;
            g_cur = g;
        }
        acc += v;
    }
    atomAdd(gpool + g_cur * 32 + c, acc);
}

// ---- final: gm = gpool/cnt ; out = gm @ fc^T ----
__global__ void final_k(const float* __restrict__ gpool, const int* __restrict__ starts,
                        const float* __restrict__ fc, float* __restrict__ out) {
    int t = blockIdx.x * blockDim.x + threadIdx.x;
    if (t >= NG * 10) return;
    int g = t / 10, j = t - g * 10;
    float cg = (float)(starts[g + 1] - starts[g]);
    float inv = 1.f / fmaxf(cg, 1.f);
    float sv = 0.f;
#pragma unroll
    for (int ch = 0; ch < 32; ++ch) sv = fmaf(gpool[g * 32 + ch], fc[j * 32 + ch], sv);
    out[t] = sv * inv;
}

extern "C" void kernel_launch(void* const* d_in, const int* in_sizes, int n_in,
                              void* d_out, int out_size, void* d_ws, size_t ws_size,
                              hipStream_t stream) {
    const float* x     = (const float*)d_in[0];
    const int*   ei    = (const int*)d_in[1];
    const float* ea    = (const float*)d_in[2];
    const int*   batch = (const int*)d_in[3];
    const float* W1    = (const float*)d_in[4];
    const float* g1    = (const float*)d_in[5];
    const float* b1v   = (const float*)d_in[6];
    const float* W2    = (const float*)d_in[7];
    const float* g2    = (const float*)d_in[8];
    const float* b2v   = (const float*)d_in[9];
    const float* fc    = (const float*)d_in[10];
    float* ws = (float*)d_ws;

    int*    offs   = (int*)(ws + OFF_OFFS);
    float*  st1    = ws + OFF_ST1;
    float*  st2    = ws + OFF_ST2;
    float*  gpool  = ws + OFF_GPOOL;
    int*    cursor = (int*)(ws + OFF_CURSOR);
    float*  h1     = ws + OFF_H1;
    float*  h2     = ws + OFF_H2;
    float4* recs   = (float4*)(ws + OFF_RECS);
    int*    starts = (int*)(ws + OFF_STARTS);
    int*    bsum   = (int*)(ws + OFF_BOFF);

    hipMemsetAsync(ws, 0, (size_t)ZERO_FLOATS * sizeof(float), stream);
    starts_k<<<1, 128, 0, stream>>>(batch, starts);

    const int BLK = 256;
    const int EGRID = (NE + BLK - 1) / BLK;
    const int NGRID = (NN + BLK - 1) / BLK;

    deg_k<<<(NE / 4 + BLK - 1) / BLK, BLK, 0, stream>>>(ei, offs);
    scan_a<<<NSB, SBLK, 0, stream>>>(offs, bsum);
    scan_b<<<1, 256, 0, stream>>>(bsum);
    scan_c<<<NGRID, BLK, 0, stream>>>(offs, bsum, cursor);
    scatter_k<<<EGRID, BLK, 0, stream>>>(ei, ea, cursor, recs);
    conv1_gather<<<NGRID, BLK, 0, stream>>>(offs, recs, x, W1, h1);
    bn_sum<16><<<512, BLK, 0, stream>>>(h1, st1);
    conv2_gather<<<NGRID, BLK, 0, stream>>>(offs, recs, h1, st1, g1, b1v, W2, h2);
    bn_sum<32><<<512, BLK, 0, stream>>>(h2, st2);
    pool_k<<<NGRID, BLK, 0, stream>>>(h2, st2, g2, b2v, batch, gpool);
    final_k<<<3, BLK, 0, stream>>>(gpool, starts, fc, (float*)d_out);
}

// Round 6
// 669.568 us; speedup vs baseline: 12.3247x; 1.0552x over previous
//
#include <hip/hip_runtime.h>
#include <math.h>

#define NN 100000
#define NE 3200000
#define NG 64
#define EPSF 1e-5f

// ---- workspace layout (float offsets) ----
#define OFF_OFFS    0          // int[100001]+pad -- deg accumulated, scanned in place
#define OFF_ST1     100004     // 16 sum + 16 sumsq
#define OFF_ST2     100036     // 32 sum + 32 sumsq
#define OFF_GPOOL   100100     // 64*32
#define ZERO_FLOATS 102148     // everything above memset to 0
#define OFF_CURSOR  102148     // int[100000]
#define OFF_H1      202148     // float[100000*16]
#define OFF_H2      1802148    // float[100000*32]
#define OFF_RECS    5002148    // uint2[3200000] = 6.4M floats
#define OFF_STARTS  11402148   // int[65]
#define OFF_BOFF    11402216   // int[200]
// total ~11.4M floats = 45.6 MB

__device__ __forceinline__ void atomAdd(float* p, float v) {
#if defined(__gfx90a__) || defined(__gfx940__) || defined(__gfx941__) || defined(__gfx942__) || defined(__gfx950__)
    unsafeAtomicAdd(p, v);
#else
    atomicAdd(p, v);
#endif
}

__device__ __forceinline__ float eluf(float x) { return x > 0.f ? x : expm1f(x); }

#define INV65535 (1.f / 65535.f)
__device__ __forceinline__ unsigned packp(float p0, float p1) {
    unsigned a = (unsigned)__float2uint_rn(p0 * 65535.f);
    unsigned b = (unsigned)__float2uint_rn(p1 * 65535.f);
    return a | (b << 16);
}

// ---- per-graph node starts via binary search over sorted batch ----
__global__ void starts_k(const int* __restrict__ batch, int* __restrict__ starts) {
    int g = threadIdx.x;
    if (g > NG) return;
    int lo = 0, hi = NN;
    while (lo < hi) { int mid = (lo + hi) >> 1; if (batch[mid] < g) lo = mid + 1; else hi = mid; }
    starts[g] = lo;
}

// ---- in-degree histogram into offs (int atomics), 8 edges/thread ----
__global__ void deg_k(const int* __restrict__ ei, int* __restrict__ deg) {
    int t = blockIdx.x * blockDim.x + threadIdx.x;
    int base = t * 8;
    if (base >= NE) return;
    int4 a = *(const int4*)(ei + NE + base);
    int4 b = *(const int4*)(ei + NE + base + 4);
    atomicAdd(&deg[a.x], 1); atomicAdd(&deg[a.y], 1);
    atomicAdd(&deg[a.z], 1); atomicAdd(&deg[a.w], 1);
    atomicAdd(&deg[b.x], 1); atomicAdd(&deg[b.y], 1);
    atomicAdd(&deg[b.z], 1); atomicAdd(&deg[b.w], 1);
}

// ---- 3-phase multi-block exclusive scan of offs (in place) ----
#define SBLK 512
#define NSB  ((NN + SBLK - 1) / SBLK)   // 196
__global__ void scan_a(int* __restrict__ offs, int* __restrict__ bsum) {
    __shared__ int s[SBLK];
    int i = blockIdx.x * SBLK + threadIdx.x;
    int v = (i < NN) ? offs[i] : 0;
    s[threadIdx.x] = v;
    __syncthreads();
    for (int d = 1; d < SBLK; d <<= 1) {
        int t = (threadIdx.x >= (unsigned)d) ? s[threadIdx.x - d] : 0;
        __syncthreads();
        s[threadIdx.x] += t;
        __syncthreads();
    }
    if (i < NN) offs[i] = s[threadIdx.x] - v;   // exclusive within block
    if (threadIdx.x == SBLK - 1) bsum[blockIdx.x] = s[SBLK - 1];
}
__global__ void scan_b(int* __restrict__ bsum) {
    __shared__ int s[256];
    int v = (threadIdx.x < NSB) ? bsum[threadIdx.x] : 0;
    s[threadIdx.x] = v;
    __syncthreads();
    for (int d = 1; d < 256; d <<= 1) {
        int t = (threadIdx.x >= (unsigned)d) ? s[threadIdx.x - d] : 0;
        __syncthreads();
        s[threadIdx.x] += t;
        __syncthreads();
    }
    if (threadIdx.x < NSB) bsum[threadIdx.x] = s[threadIdx.x] - v;  // exclusive
}
__global__ void scan_c(int* __restrict__ offs, const int* __restrict__ bsum,
                       int* __restrict__ cursor) {
    int i = blockIdx.x * blockDim.x + threadIdx.x;
    if (i < NN) {
        int o = offs[i] + bsum[i / SBLK];
        offs[i] = o;
        cursor[i] = o;
    }
    if (i == 0) offs[NN] = NE;
}

// ---- scatter edges into CSR order: 8 edges/thread (ILP), 8B packed recs ----
__global__ void scatter_k(const int* __restrict__ ei, const float* __restrict__ ea,
                          int* __restrict__ cursor, uint2* __restrict__ recs) {
    int t = blockIdx.x * blockDim.x + threadIdx.x;
    int base = t * 8;
    if (base >= NE) return;
    int4 d0 = *(const int4*)(ei + NE + base);
    int4 d1 = *(const int4*)(ei + NE + base + 4);
    int4 s0 = *(const int4*)(ei + base);
    int4 s1 = *(const int4*)(ei + base + 4);
    float4 pA = *(const float4*)(ea + 2 * base);
    float4 pB = *(const float4*)(ea + 2 * base + 4);
    float4 pC = *(const float4*)(ea + 2 * base + 8);
    float4 pD = *(const float4*)(ea + 2 * base + 12);
    // 8 independent atomics in flight
    int q0 = atomicAdd(&cursor[d0.x], 1);
    int q1 = atomicAdd(&cursor[d0.y], 1);
    int q2 = atomicAdd(&cursor[d0.z], 1);
    int q3 = atomicAdd(&cursor[d0.w], 1);
    int q4 = atomicAdd(&cursor[d1.x], 1);
    int q5 = atomicAdd(&cursor[d1.y], 1);
    int q6 = atomicAdd(&cursor[d1.z], 1);
    int q7 = atomicAdd(&cursor[d1.w], 1);
    recs[q0] = make_uint2((unsigned)s0.x, packp(pA.x, pA.y));
    recs[q1] = make_uint2((unsigned)s0.y, packp(pA.z, pA.w));
    recs[q2] = make_uint2((unsigned)s0.z, packp(pB.x, pB.y));
    recs[q3] = make_uint2((unsigned)s0.w, packp(pB.z, pB.w));
    recs[q4] = make_uint2((unsigned)s1.x, packp(pC.x, pC.y));
    recs[q5] = make_uint2((unsigned)s1.y, packp(pC.z, pC.w));
    recs[q6] = make_uint2((unsigned)s1.z, packp(pD.x, pD.y));
    recs[q7] = make_uint2((unsigned)s1.w, packp(pD.z, pD.w));
}

// ---- conv1: gather per node, T[4][3] in regs, 12x16 GEMV ----
__global__ void __launch_bounds__(256) conv1_gather(const int* __restrict__ offs,
        const uint2* __restrict__ recs, const float* __restrict__ x,
        const float* __restrict__ W1, float* __restrict__ h1) {
    __shared__ float sW[192];
    if (threadIdx.x < 192) sW[threadIdx.x] = W1[threadIdx.x];
    __syncthreads();
    int n = blockIdx.x * blockDim.x + threadIdx.x;
    if (n >= NN) return;
    int off = offs[n], end = offs[n + 1];
    float T[12];
#pragma unroll
    for (int i = 0; i < 12; ++i) T[i] = 0.f;
    for (int e = off; e < end; ++e) {
        uint2 r = recs[e];
        int s = (int)r.x;
        float p0 = (float)(r.y & 0xffffu) * INV65535;
        float p1 = (float)(r.y >> 16) * INV65535;
        float b0 = (1.f - p1) * (1.f - p0), b1 = (1.f - p1) * p0;
        float b2 = p1 * (1.f - p0), b3 = p1 * p0;
        float x0 = x[3 * s], x1 = x[3 * s + 1], x2 = x[3 * s + 2];
        T[0] = fmaf(b0, x0, T[0]);  T[1] = fmaf(b0, x1, T[1]);  T[2]  = fmaf(b0, x2, T[2]);
        T[3] = fmaf(b1, x0, T[3]);  T[4] = fmaf(b1, x1, T[4]);  T[5]  = fmaf(b1, x2, T[5]);
        T[6] = fmaf(b2, x0, T[6]);  T[7] = fmaf(b2, x1, T[7]);  T[8]  = fmaf(b2, x2, T[8]);
        T[9] = fmaf(b3, x0, T[9]);  T[10]= fmaf(b3, x1, T[10]); T[11] = fmaf(b3, x2, T[11]);
    }
    float inv = 1.f / fmaxf((float)(end - off), 1.f);
    float ov[16];
#pragma unroll
    for (int o = 0; o < 16; ++o) {
        float acc = 0.f;
#pragma unroll
        for (int k = 0; k < 4; ++k)
#pragma unroll
            for (int i = 0; i < 3; ++i)
                acc = fmaf(T[k * 3 + i], sW[k * 48 + i * 16 + o], acc);
        acc *= inv;
        ov[o] = eluf(acc);
    }
    float4* hp = (float4*)(h1 + (long)n * 16);
#pragma unroll
    for (int q = 0; q < 4; ++q)
        hp[q] = make_float4(ov[4 * q], ov[4 * q + 1], ov[4 * q + 2], ov[4 * q + 3]);
}

// ---- BN stats: plain sum/sumsq over h (C channels) ----
template <int C>
__global__ void bn_sum(const float* __restrict__ h, float* __restrict__ st) {
    __shared__ float ss[C], sq[C];
    if (threadIdx.x < C) { ss[threadIdx.x] = 0.f; sq[threadIdx.x] = 0.f; }
    __syncthreads();
    const int total = NN * C;
    const int stride = gridDim.x * blockDim.x;
    float a = 0.f, q = 0.f;
    for (int i = blockIdx.x * blockDim.x + threadIdx.x; i < total; i += stride) {
        float v = h[i];
        a += v; q += v * v;
    }
#pragma unroll
    for (int d = C; d < 64; d <<= 1) { a += __shfl_xor(a, d); q += __shfl_xor(q, d); }
    int lane = threadIdx.x & 63;
    if (lane < C) { atomicAdd(&ss[lane], a); atomicAdd(&sq[lane], q); }
    __syncthreads();
    if (threadIdx.x < C) {
        atomAdd(&st[threadIdx.x], ss[threadIdx.x]);
        atomAdd(&st[C + threadIdx.x], sq[threadIdx.x]);
    }
}

// ---- conv2: gather per node, U[64]+S[4] in regs, 64x32 GEMV vs LDS W2' ----
__global__ void __launch_bounds__(256) conv2_gather(const int* __restrict__ offs,
        const uint2* __restrict__ recs, const float* __restrict__ h1,
        const float* __restrict__ st1, const float* __restrict__ g1,
        const float* __restrict__ b1v, const float* __restrict__ W2,
        float* __restrict__ h2) {
    __shared__ float s_sc[16], s_sh[16];
    __shared__ float sWp[2048];  // sc_i * W2[k][i][o]
    __shared__ float sV[128];    // sum_i sh_i * W2[k][i][o]
    if (threadIdx.x < 16) {
        int c = threadIdx.x;
        float mu = st1[c] * (1.f / NN);
        float var = st1[16 + c] * (1.f / NN) - mu * mu;
        float rs = rsqrtf(var + EPSF);
        float s = g1[c] * rs;
        s_sc[c] = s;
        s_sh[c] = b1v[c] - mu * s;
    }
    __syncthreads();
    for (int idx = threadIdx.x; idx < 2048; idx += blockDim.x) {
        int i = (idx & 511) >> 5;
        sWp[idx] = s_sc[i] * W2[idx];
    }
    if (threadIdx.x < 128) {
        int k = threadIdx.x >> 5, o = threadIdx.x & 31;
        float acc = 0.f;
#pragma unroll
        for (int i = 0; i < 16; ++i) acc = fmaf(s_sh[i], W2[k * 512 + i * 32 + o], acc);
        sV[threadIdx.x] = acc;
    }
    __syncthreads();
    int n = blockIdx.x * blockDim.x + threadIdx.x;
    if (n >= NN) return;
    int off = offs[n], end = offs[n + 1];
    float U[64];
    float S0 = 0.f, S1 = 0.f, S2 = 0.f, S3 = 0.f;
#pragma unroll
    for (int i = 0; i < 64; ++i) U[i] = 0.f;
    for (int e = off; e < end; ++e) {
        uint2 r = recs[e];
        int s = (int)r.x;
        float p0 = (float)(r.y & 0xffffu) * INV65535;
        float p1 = (float)(r.y >> 16) * INV65535;
        float b0 = (1.f - p1) * (1.f - p0), b1 = (1.f - p1) * p0;
        float b2 = p1 * (1.f - p0), b3 = p1 * p0;
        const float4* hp = (const float4*)(h1 + (long)s * 16);
        float4 t0 = hp[0], t1 = hp[1], t2 = hp[2], t3 = hp[3];
        float hv[16] = {t0.x, t0.y, t0.z, t0.w, t1.x, t1.y, t1.z, t1.w,
                        t2.x, t2.y, t2.z, t2.w, t3.x, t3.y, t3.z, t3.w};
#pragma unroll
        for (int i = 0; i < 16; ++i) {
            U[i]      = fmaf(b0, hv[i], U[i]);
            U[16 + i] = fmaf(b1, hv[i], U[16 + i]);
            U[32 + i] = fmaf(b2, hv[i], U[32 + i]);
            U[48 + i] = fmaf(b3, hv[i], U[48 + i]);
        }
        S0 += b0; S1 += b1; S2 += b2; S3 += b3;
    }
    float inv = 1.f / fmaxf((float)(end - off), 1.f);
    float4 acc[8];
#pragma unroll
    for (int ob = 0; ob < 8; ++ob) acc[ob] = make_float4(0.f, 0.f, 0.f, 0.f);
    const float4* Wp4 = (const float4*)sWp;
#pragma unroll 4
    for (int ki = 0; ki < 64; ++ki) {
        float u = U[ki];
#pragma unroll
        for (int ob = 0; ob < 8; ++ob) {
            float4 w = Wp4[ki * 8 + ob];
            acc[ob].x = fmaf(u, w.x, acc[ob].x);
            acc[ob].y = fmaf(u, w.y, acc[ob].y);
            acc[ob].z = fmaf(u, w.z, acc[ob].z);
            acc[ob].w = fmaf(u, w.w, acc[ob].w);
        }
    }
    const float4* V4 = (const float4*)sV;
    float Sarr[4] = {S0, S1, S2, S3};
#pragma unroll
    for (int k = 0; k < 4; ++k) {
        float u = Sarr[k];
#pragma unroll
        for (int ob = 0; ob < 8; ++ob) {
            float4 w = V4[k * 8 + ob];
            acc[ob].x = fmaf(u, w.x, acc[ob].x);
            acc[ob].y = fmaf(u, w.y, acc[ob].y);
            acc[ob].z = fmaf(u, w.z, acc[ob].z);
            acc[ob].w = fmaf(u, w.w, acc[ob].w);
        }
    }
    float4* out4 = (float4*)(h2 + (long)n * 32);
#pragma unroll
    for (int ob = 0; ob < 8; ++ob) {
        float4 a = acc[ob];
        a.x = eluf(a.x * inv); a.y = eluf(a.y * inv);
        a.z = eluf(a.z * inv); a.w = eluf(a.w * inv);
        out4[ob] = a;
    }
}

// ---- per-graph mean pool with BN2 affine, exploiting sorted batch ----
__global__ void pool_k(const float* __restrict__ h2pre, const float* __restrict__ st2,
                       const float* __restrict__ g2, const float* __restrict__ b2v,
                       const int* __restrict__ batch, float* __restrict__ gpool) {
    int t = blockIdx.x * blockDim.x + threadIdx.x;
    int c = t & 31;
    int chunk = t >> 5;
    if (chunk >= NN / 32) return;
    float mu = st2[c] * (1.f / NN);
    float var = st2[32 + c] * (1.f / NN) - mu * mu;
    float rs = rsqrtf(var + EPSF);
    float s = g2[c] * rs;
    float sh = b2v[c] - mu * s;
    int n0 = chunk * 32;
    int g_cur = batch[n0];
    float acc = 0.f;
    for (int i = 0; i < 32; ++i) {
        int n = n0 + i;
        int g = batch[n];
        float v = fmaf(h2pre[(long)n * 32 + c], s, sh);
        if (g != g_cur) {
            atomAdd(gpool + g_cur * 32 + c, acc);
            acc = 0.f;
            g_cur = g;
        }
        acc += v;
    }
    atomAdd(gpool + g_cur * 32 + c, acc);
}

// ---- final: gm = gpool/cnt ; out = gm @ fc^T ----
__global__ void final_k(const float* __restrict__ gpool, const int* __restrict__ starts,
                        const float* __restrict__ fc, float* __restrict__ out) {
    int t = blockIdx.x * blockDim.x + threadIdx.x;
    if (t >= NG * 10) return;
    int g = t / 10, j = t - g * 10;
    float cg = (float)(starts[g + 1] - starts[g]);
    float inv = 1.f / fmaxf(cg, 1.f);
    float sv = 0.f;
#pragma unroll
    for (int ch = 0; ch < 32; ++ch) sv = fmaf(gpool[g * 32 + ch], fc[j * 32 + ch], sv);
    out[t] = sv * inv;
}

extern "C" void kernel_launch(void* const* d_in, const int* in_sizes, int n_in,
                              void* d_out, int out_size, void* d_ws, size_t ws_size,
                              hipStream_t stream) {
    const float* x     = (const float*)d_in[0];
    const int*   ei    = (const int*)d_in[1];
    const float* ea    = (const float*)d_in[2];
    const int*   batch = (const int*)d_in[3];
    const float* W1    = (const float*)d_in[4];
    const float* g1    = (const float*)d_in[5];
    const float* b1v   = (const float*)d_in[6];
    const float* W2    = (const float*)d_in[7];
    const float* g2    = (const float*)d_in[8];
    const float* b2v   = (const float*)d_in[9];
    const float* fc    = (const float*)d_in[10];
    float* ws = (float*)d_ws;

    int*    offs   = (int*)(ws + OFF_OFFS);
    float*  st1    = ws + OFF_ST1;
    float*  st2    = ws + OFF_ST2;
    float*  gpool  = ws + OFF_GPOOL;
    int*    cursor = (int*)(ws + OFF_CURSOR);
    float*  h1     = ws + OFF_H1;
    float*  h2     = ws + OFF_H2;
    uint2*  recs   = (uint2*)(ws + OFF_RECS);
    int*    starts = (int*)(ws + OFF_STARTS);
    int*    bsum   = (int*)(ws + OFF_BOFF);

    hipMemsetAsync(ws, 0, (size_t)ZERO_FLOATS * sizeof(float), stream);
    starts_k<<<1, 128, 0, stream>>>(batch, starts);

    const int BLK = 256;
    const int NGRID = (NN + BLK - 1) / BLK;

    deg_k<<<(NE / 8 + BLK - 1) / BLK, BLK, 0, stream>>>(ei, offs);
    scan_a<<<NSB, SBLK, 0, stream>>>(offs, bsum);
    scan_b<<<1, 256, 0, stream>>>(bsum);
    scan_c<<<NGRID, BLK, 0, stream>>>(offs, bsum, cursor);
    scatter_k<<<(NE / 8 + BLK - 1) / BLK, BLK, 0, stream>>>(ei, ea, cursor, recs);
    conv1_gather<<<NGRID, BLK, 0, stream>>>(offs, recs, x, W1, h1);
    bn_sum<16><<<512, BLK, 0, stream>>>(h1, st1);
    conv2_gather<<<NGRID, BLK, 0, stream>>>(offs, recs, h1, st1, g1, b1v, W2, h2);
    bn_sum<32><<<512, BLK, 0, stream>>>(h2, st2);
    pool_k<<<NGRID, BLK, 0, stream>>>(h2, st2, g2, b2v, batch, gpool);
    final_k<<<3, BLK, 0, stream>>>(gpool, starts, fc, (float*)d_out);
}

// Round 7
// 608.056 us; speedup vs baseline: 13.5715x; 1.1012x over previous
//
#include <hip/hip_runtime.h>
#include <math.h>

#define NN 100000
#define NE 3200000
#define NG 64
#define EPSF 1e-5f
#define NB 98        // buckets = ceil(NN / 1024)
#define BSH 10       // bucket shift: dst >> 10

// ---- workspace layout (float offsets) ----
#define OFF_OFFS    0          // int[100001]+pad -- deg accumulated, scanned in place
#define OFF_ST1     100004     // 16 sum + 16 sumsq
#define OFF_ST2     100036     // 32 sum + 32 sumsq
#define OFF_GPOOL   100100     // 64*32
#define ZERO_FLOATS 102148     // everything above memset to 0
#define OFF_BCUR    102148     // int[98] (init by scan_c)
#define OFF_CURSOR  102248     // int[100000] (init by scan_c)
#define OFF_H1      202248     // float[100000*16]
#define OFF_H2      1802248    // float[100000*32]
#define OFF_RECSA   5002248    // uint2[3200000]
#define OFF_RECSB   11402248   // uint2[3200000]
#define OFF_STARTS  17802248   // int[65]
#define OFF_BOFF    17802320   // int[200]

__device__ __forceinline__ void atomAdd(float* p, float v) {
#if defined(__gfx90a__) || defined(__gfx940__) || defined(__gfx941__) || defined(__gfx942__) || defined(__gfx950__)
    unsafeAtomicAdd(p, v);
#else
    atomicAdd(p, v);
#endif
}

__device__ __forceinline__ float eluf(float x) { return x > 0.f ? x : expm1f(x); }

#define INV32767 (1.f / 32767.f)

// ---- per-graph node starts via binary search over sorted batch ----
__global__ void starts_k(const int* __restrict__ batch, int* __restrict__ starts) {
    int g = threadIdx.x;
    if (g > NG) return;
    int lo = 0, hi = NN;
    while (lo < hi) { int mid = (lo + hi) >> 1; if (batch[mid] < g) lo = mid + 1; else hi = mid; }
    starts[g] = lo;
}

// ---- in-degree histogram into offs (int atomics), 8 edges/thread ----
__global__ void deg_k(const int* __restrict__ ei, int* __restrict__ deg) {
    int t = blockIdx.x * blockDim.x + threadIdx.x;
    int base = t * 8;
    if (base >= NE) return;
    int4 a = *(const int4*)(ei + NE + base);
    int4 b = *(const int4*)(ei + NE + base + 4);
    atomicAdd(&deg[a.x], 1); atomicAdd(&deg[a.y], 1);
    atomicAdd(&deg[a.z], 1); atomicAdd(&deg[a.w], 1);
    atomicAdd(&deg[b.x], 1); atomicAdd(&deg[b.y], 1);
    atomicAdd(&deg[b.z], 1); atomicAdd(&deg[b.w], 1);
}

// ---- 3-phase multi-block exclusive scan of offs (in place) ----
#define SBLK 512
#define NSB  ((NN + SBLK - 1) / SBLK)   // 196
__global__ void scan_a(int* __restrict__ offs, int* __restrict__ bsum) {
    __shared__ int s[SBLK];
    int i = blockIdx.x * SBLK + threadIdx.x;
    int v = (i < NN) ? offs[i] : 0;
    s[threadIdx.x] = v;
    __syncthreads();
    for (int d = 1; d < SBLK; d <<= 1) {
        int t = (threadIdx.x >= (unsigned)d) ? s[threadIdx.x - d] : 0;
        __syncthreads();
        s[threadIdx.x] += t;
        __syncthreads();
    }
    if (i < NN) offs[i] = s[threadIdx.x] - v;   // exclusive within block
    if (threadIdx.x == SBLK - 1) bsum[blockIdx.x] = s[SBLK - 1];
}
__global__ void scan_b(int* __restrict__ bsum) {
    __shared__ int s[256];
    int v = (threadIdx.x < NSB) ? bsum[threadIdx.x] : 0;
    s[threadIdx.x] = v;
    __syncthreads();
    for (int d = 1; d < 256; d <<= 1) {
        int t = (threadIdx.x >= (unsigned)d) ? s[threadIdx.x - d] : 0;
        __syncthreads();
        s[threadIdx.x] += t;
        __syncthreads();
    }
    if (threadIdx.x < NSB) bsum[threadIdx.x] = s[threadIdx.x] - v;  // exclusive
}
__global__ void scan_c(int* __restrict__ offs, const int* __restrict__ bsum,
                       int* __restrict__ cursor, int* __restrict__ bcur) {
    int i = blockIdx.x * blockDim.x + threadIdx.x;
    if (i < NN) {
        int o = offs[i] + bsum[i / SBLK];
        offs[i] = o;
        cursor[i] = o;
        if ((i & 1023) == 0) bcur[i >> BSH] = o;  // bucket base cursor
    }
    if (i == 0) offs[NN] = NE;
}

// ---- pass A: route edges into 98 dst-range buckets (coarse, write-friendly) ----
// 256 thr x 16 edges = 4096-edge chunks. LDS hist -> 1 global atomic per
// (wg,bucket) -> LDS cursor gives global position. Writes land in ~340B
// contiguous runs per (wg,bucket) instead of isolated 8B scatters.
__global__ void __launch_bounds__(256) passA(const int* __restrict__ ei,
        const float* __restrict__ ea, int* __restrict__ bcur,
        uint2* __restrict__ recsA) {
    __shared__ int lh[NB];
    __shared__ int gcur[NB];
    int tid = threadIdx.x;
    if (tid < NB) lh[tid] = 0;
    __syncthreads();
    int base = blockIdx.x * 4096;
    uint2 rec[16];
    int bk[16];
#pragma unroll
    for (int j = 0; j < 16; ++j) {
        int e = base + j * 256 + tid;
        bk[j] = -1;
        if (e < NE) {
            int src = ei[e];
            int dst = ei[NE + e];
            float2 p = ((const float2*)ea)[e];
            unsigned q0 = (unsigned)__float2uint_rn(p.x * 32767.f);
            unsigned q1 = (unsigned)__float2uint_rn(p.y * 32767.f);
            rec[j] = make_uint2((unsigned)src | (q0 << 17), (unsigned)dst | (q1 << 17));
            bk[j] = dst >> BSH;
            atomicAdd(&lh[bk[j]], 1);
        }
    }
    __syncthreads();
    if (tid < NB) gcur[tid] = atomicAdd(&bcur[tid], lh[tid]);
    __syncthreads();
#pragma unroll
    for (int j = 0; j < 16; ++j) {
        if (bk[j] >= 0) {
            int pos = atomicAdd(&gcur[bk[j]], 1);
            recsA[pos] = rec[j];
        }
    }
}

// ---- pass B: fine scatter within buckets (dst region is L2-resident) ----
// Chunk->XCD swizzle keeps each bucket's records on one XCD's L2.
__global__ void __launch_bounds__(256) passB(const uint2* __restrict__ recsA,
        int* __restrict__ cursor, uint2* __restrict__ recsB) {
    int nwg = gridDim.x;
    int d = blockIdx.x;
    int q = nwg >> 3, r = nwg & 7;
    int xcd = d & 7, idx = d >> 3;
    int chunk = (xcd < r) ? (xcd * (q + 1) + idx)
                          : (r * (q + 1) + (xcd - r) * q + idx);
    int base = chunk * 2048;
#pragma unroll
    for (int j = 0; j < 8; ++j) {
        int i = base + j * 256 + threadIdx.x;
        if (i < NE) {
            uint2 rc = recsA[i];
            int dst = rc.y & 0x1FFFF;
            int pos = atomicAdd(&cursor[dst], 1);
            recsB[pos] = rc;
        }
    }
}

// ---- conv1: gather per node, T[4][3] in regs, 12x16 GEMV ----
__global__ void __launch_bounds__(256) conv1_gather(const int* __restrict__ offs,
        const uint2* __restrict__ recs, const float* __restrict__ x,
        const float* __restrict__ W1, float* __restrict__ h1) {
    __shared__ float sW[192];
    if (threadIdx.x < 192) sW[threadIdx.x] = W1[threadIdx.x];
    __syncthreads();
    int n = blockIdx.x * blockDim.x + threadIdx.x;
    if (n >= NN) return;
    int off = offs[n], end = offs[n + 1];
    float T[12];
#pragma unroll
    for (int i = 0; i < 12; ++i) T[i] = 0.f;
    for (int e = off; e < end; ++e) {
        uint2 r = recs[e];
        int s = (int)(r.x & 0x1FFFFu);
        float p0 = (float)(r.x >> 17) * INV32767;
        float p1 = (float)(r.y >> 17) * INV32767;
        float b0 = (1.f - p1) * (1.f - p0), b1 = (1.f - p1) * p0;
        float b2 = p1 * (1.f - p0), b3 = p1 * p0;
        float x0 = x[3 * s], x1 = x[3 * s + 1], x2 = x[3 * s + 2];
        T[0] = fmaf(b0, x0, T[0]);  T[1] = fmaf(b0, x1, T[1]);  T[2]  = fmaf(b0, x2, T[2]);
        T[3] = fmaf(b1, x0, T[3]);  T[4] = fmaf(b1, x1, T[4]);  T[5]  = fmaf(b1, x2, T[5]);
        T[6] = fmaf(b2, x0, T[6]);  T[7] = fmaf(b2, x1, T[7]);  T[8]  = fmaf(b2, x2, T[8]);
        T[9] = fmaf(b3, x0, T[9]);  T[10]= fmaf(b3, x1, T[10]); T[11] = fmaf(b3, x2, T[11]);
    }
    float inv = 1.f / fmaxf((float)(end - off), 1.f);
    float ov[16];
#pragma unroll
    for (int o = 0; o < 16; ++o) {
        float acc = 0.f;
#pragma unroll
        for (int k = 0; k < 4; ++k)
#pragma unroll
            for (int i = 0; i < 3; ++i)
                acc = fmaf(T[k * 3 + i], sW[k * 48 + i * 16 + o], acc);
        acc *= inv;
        ov[o] = eluf(acc);
    }
    float4* hp = (float4*)(h1 + (long)n * 16);
#pragma unroll
    for (int q = 0; q < 4; ++q)
        hp[q] = make_float4(ov[4 * q], ov[4 * q + 1], ov[4 * q + 2], ov[4 * q + 3]);
}

// ---- BN stats: plain sum/sumsq over h (C channels) ----
template <int C>
__global__ void bn_sum(const float* __restrict__ h, float* __restrict__ st) {
    __shared__ float ss[C], sq[C];
    if (threadIdx.x < C) { ss[threadIdx.x] = 0.f; sq[threadIdx.x] = 0.f; }
    __syncthreads();
    const int total = NN * C;
    const int stride = gridDim.x * blockDim.x;
    float a = 0.f, q = 0.f;
    for (int i = blockIdx.x * blockDim.x + threadIdx.x; i < total; i += stride) {
        float v = h[i];
        a += v; q += v * v;
    }
#pragma unroll
    for (int d = C; d < 64; d <<= 1) { a += __shfl_xor(a, d); q += __shfl_xor(q, d); }
    int lane = threadIdx.x & 63;
    if (lane < C) { atomicAdd(&ss[lane], a); atomicAdd(&sq[lane], q); }
    __syncthreads();
    if (threadIdx.x < C) {
        atomAdd(&st[threadIdx.x], ss[threadIdx.x]);
        atomAdd(&st[C + threadIdx.x], sq[threadIdx.x]);
    }
}

// ---- conv2: gather per node, U[64]+S[4] in regs, 64x32 GEMV vs LDS W2' ----
__global__ void __launch_bounds__(256) conv2_gather(const int* __restrict__ offs,
        const uint2* __restrict__ recs, const float* __restrict__ h1,
        const float* __restrict__ st1, const float* __restrict__ g1,
        const float* __restrict__ b1v, const float* __restrict__ W2,
        float* __restrict__ h2) {
    __shared__ float s_sc[16], s_sh[16];
    __shared__ float sWp[2048];  // sc_i * W2[k][i][o]
    __shared__ float sV[128];    // sum_i sh_i * W2[k][i][o]
    if (threadIdx.x < 16) {
        int c = threadIdx.x;
        float mu = st1[c] * (1.f / NN);
        float var = st1[16 + c] * (1.f / NN) - mu * mu;
        float rs = rsqrtf(var + EPSF);
        float s = g1[c] * rs;
        s_sc[c] = s;
        s_sh[c] = b1v[c] - mu * s;
    }
    __syncthreads();
    for (int idx = threadIdx.x; idx < 2048; idx += blockDim.x) {
        int i = (idx & 511) >> 5;
        sWp[idx] = s_sc[i] * W2[idx];
    }
    if (threadIdx.x < 128) {
        int k = threadIdx.x >> 5, o = threadIdx.x & 31;
        float acc = 0.f;
#pragma unroll
        for (int i = 0; i < 16; ++i) acc = fmaf(s_sh[i], W2[k * 512 + i * 32 + o], acc);
        sV[threadIdx.x] = acc;
    }
    __syncthreads();
    int n = blockIdx.x * blockDim.x + threadIdx.x;
    if (n >= NN) return;
    int off = offs[n], end = offs[n + 1];
    float U[64];
    float S0 = 0.f, S1 = 0.f, S2 = 0.f, S3 = 0.f;
#pragma unroll
    for (int i = 0; i < 64; ++i) U[i] = 0.f;
    for (int e = off; e < end; ++e) {
        uint2 r = recs[e];
        int s = (int)(r.x & 0x1FFFFu);
        float p0 = (float)(r.x >> 17) * INV32767;
        float p1 = (float)(r.y >> 17) * INV32767;
        float b0 = (1.f - p1) * (1.f - p0), b1 = (1.f - p1) * p0;
        float b2 = p1 * (1.f - p0), b3 = p1 * p0;
        const float4* hp = (const float4*)(h1 + (long)s * 16);
        float4 t0 = hp[0], t1 = hp[1], t2 = hp[2], t3 = hp[3];
        float hv[16] = {t0.x, t0.y, t0.z, t0.w, t1.x, t1.y, t1.z, t1.w,
                        t2.x, t2.y, t2.z, t2.w, t3.x, t3.y, t3.z, t3.w};
#pragma unroll
        for (int i = 0; i < 16; ++i) {
            U[i]      = fmaf(b0, hv[i], U[i]);
            U[16 + i] = fmaf(b1, hv[i], U[16 + i]);
            U[32 + i] = fmaf(b2, hv[i], U[32 + i]);
            U[48 + i] = fmaf(b3, hv[i], U[48 + i]);
        }
        S0 += b0; S1 += b1; S2 += b2; S3 += b3;
    }
    float inv = 1.f / fmaxf((float)(end - off), 1.f);
    float4 acc[8];
#pragma unroll
    for (int ob = 0; ob < 8; ++ob) acc[ob] = make_float4(0.f, 0.f, 0.f, 0.f);
    const float4* Wp4 = (const float4*)sWp;
#pragma unroll 4
    for (int ki = 0; ki < 64; ++ki) {
        float u = U[ki];
#pragma unroll
        for (int ob = 0; ob < 8; ++ob) {
            float4 w = Wp4[ki * 8 + ob];
            acc[ob].x = fmaf(u, w.x, acc[ob].x);
            acc[ob].y = fmaf(u, w.y, acc[ob].y);
            acc[ob].z = fmaf(u, w.z, acc[ob].z);
            acc[ob].w = fmaf(u, w.w, acc[ob].w);
        }
    }
    const float4* V4 = (const float4*)sV;
    float Sarr[4] = {S0, S1, S2, S3};
#pragma unroll
    for (int k = 0; k < 4; ++k) {
        float u = Sarr[k];
#pragma unroll
        for (int ob = 0; ob < 8; ++ob) {
            float4 w = V4[k * 8 + ob];
            acc[ob].x = fmaf(u, w.x, acc[ob].x);
            acc[ob].y = fmaf(u, w.y, acc[ob].y);
            acc[ob].z = fmaf(u, w.z, acc[ob].z);
            acc[ob].w = fmaf(u, w.w, acc[ob].w);
        }
    }
    float4* out4 = (float4*)(h2 + (long)n * 32);
#pragma unroll
    for (int ob = 0; ob < 8; ++ob) {
        float4 a = acc[ob];
        a.x = eluf(a.x * inv); a.y = eluf(a.y * inv);
        a.z = eluf(a.z * inv); a.w = eluf(a.w * inv);
        out4[ob] = a;
    }
}

// ---- per-graph mean pool with BN2 affine, exploiting sorted batch ----
__global__ void pool_k(const float* __restrict__ h2pre, const float* __restrict__ st2,
                       const float* __restrict__ g2, const float* __restrict__ b2v,
                       const int* __restrict__ batch, float* __restrict__ gpool) {
    int t = blockIdx.x * blockDim.x + threadIdx.x;
    int c = t & 31;
    int chunk = t >> 5;
    if (chunk >= NN / 32) return;
    float mu = st2[c] * (1.f / NN);
    float var = st2[32 + c] * (1.f / NN) - mu * mu;
    float rs = rsqrtf(var + EPSF);
    float s = g2[c] * rs;
    float sh = b2v[c] - mu * s;
    int n0 = chunk * 32;
    int g_cur = batch[n0];
    float acc = 0.f;
    for (int i = 0; i < 32; ++i) {
        int n = n0 + i;
        int g = batch[n];
        float v = fmaf(h2pre[(long)n * 32 + c], s, sh);
        if (g != g_cur) {
            atomAdd(gpool + g_cur * 32 + c, acc);
            acc = 0.f;
            g_cur = g;
        }
        acc += v;
    }
    atomAdd(gpool + g_cur * 32 + c, acc);
}

// ---- final: gm = gpool/cnt ; out = gm @ fc^T ----
__global__ void final_k(const float* __restrict__ gpool, const int* __restrict__ starts,
                        const float* __restrict__ fc, float* __restrict__ out) {
    int t = blockIdx.x * blockDim.x + threadIdx.x;
    if (t >= NG * 10) return;
    int g = t / 10, j = t - g * 10;
    float cg = (float)(starts[g + 1] - starts[g]);
    float inv = 1.f / fmaxf(cg, 1.f);
    float sv = 0.f;
#pragma unroll
    for (int ch = 0; ch < 32; ++ch) sv = fmaf(gpool[g * 32 + ch], fc[j * 32 + ch], sv);
    out[t] = sv * inv;
}

extern "C" void kernel_launch(void* const* d_in, const int* in_sizes, int n_in,
                              void* d_out, int out_size, void* d_ws, size_t ws_size,
                              hipStream_t stream) {
    const float* x     = (const float*)d_in[0];
    const int*   ei    = (const int*)d_in[1];
    const float* ea    = (const float*)d_in[2];
    const int*   batch = (const int*)d_in[3];
    const float* W1    = (const float*)d_in[4];
    const float* g1    = (const float*)d_in[5];
    const float* b1v   = (const float*)d_in[6];
    const float* W2    = (const float*)d_in[7];
    const float* g2    = (const float*)d_in[8];
    const float* b2v   = (const float*)d_in[9];
    const float* fc    = (const float*)d_in[10];
    float* ws = (float*)d_ws;

    int*    offs   = (int*)(ws + OFF_OFFS);
    float*  st1    = ws + OFF_ST1;
    float*  st2    = ws + OFF_ST2;
    float*  gpool  = ws + OFF_GPOOL;
    int*    bcur   = (int*)(ws + OFF_BCUR);
    int*    cursor = (int*)(ws + OFF_CURSOR);
    float*  h1     = ws + OFF_H1;
    float*  h2     = ws + OFF_H2;
    uint2*  recsA  = (uint2*)(ws + OFF_RECSA);
    uint2*  recsB  = (uint2*)(ws + OFF_RECSB);
    int*    starts = (int*)(ws + OFF_STARTS);
    int*    bsum   = (int*)(ws + OFF_BOFF);

    hipMemsetAsync(ws, 0, (size_t)ZERO_FLOATS * sizeof(float), stream);
    starts_k<<<1, 128, 0, stream>>>(batch, starts);

    const int BLK = 256;
    const int NGRID = (NN + BLK - 1) / BLK;

    deg_k<<<(NE / 8 + BLK - 1) / BLK, BLK, 0, stream>>>(ei, offs);
    scan_a<<<NSB, SBLK, 0, stream>>>(offs, bsum);
    scan_b<<<1, 256, 0, stream>>>(bsum);
    scan_c<<<NGRID, BLK, 0, stream>>>(offs, bsum, cursor, bcur);
    passA<<<(NE + 4095) / 4096, BLK, 0, stream>>>(ei, ea, bcur, recsA);
    passB<<<(NE + 2047) / 2048, BLK, 0, stream>>>(recsA, cursor, recsB);
    conv1_gather<<<NGRID, BLK, 0, stream>>>(offs, recsB, x, W1, h1);
    bn_sum<16><<<512, BLK, 0, stream>>>(h1, st1);
    conv2_gather<<<NGRID, BLK, 0, stream>>>(offs, recsB, h1, st1, g1, b1v, W2, h2);
    bn_sum<32><<<512, BLK, 0, stream>>>(h2, st2);
    pool_k<<<NGRID, BLK, 0, stream>>>(h2, st2, g2, b2v, batch, gpool);
    final_k<<<3, BLK, 0, stream>>>(gpool, starts, fc, (float*)d_out);
}

// Round 8
// 381.275 us; speedup vs baseline: 21.6438x; 1.5948x over previous
//
#include <hip/hip_runtime.h>
#include <math.h>

#define NN 100000
#define NE 3200000
#define NG 64
#define EPSF 1e-5f
#define NB 391       // buckets of 256 nodes: ceil(100000/256)
#define BSH 8        // bucket = dst >> 8

// ---- workspace layout (float offsets) ----
#define OFF_ST1     0          // 16 sum + 16 sumsq
#define OFF_ST2     32         // 32 sum + 32 sumsq
#define OFF_GPOOL   96         // 64*32
#define OFF_BCNT    2144       // int[392]
#define ZERO_FLOATS 2536       // everything above memset to 0
#define OFF_BBASE   2536       // int[392]
#define OFF_BCUR    2928       // int[392]
#define OFF_OFFS    3320       // int[100001]
#define OFF_STARTS  103324     // int[65]
#define OFF_H1      103392     // float[100000*16]  (%4==0)
#define OFF_H2      1703392    // float[100000*32]  (%4==0)
#define OFF_RECSA   4903392    // uint2[3200000]
#define OFF_RECSB   11303392   // uint2[3200000]
// total ~17.7M floats = 70.8 MB

__device__ __forceinline__ void atomAdd(float* p, float v) {
#if defined(__gfx90a__) || defined(__gfx940__) || defined(__gfx941__) || defined(__gfx942__) || defined(__gfx950__)
    unsafeAtomicAdd(p, v);
#else
    atomicAdd(p, v);
#endif
}

__device__ __forceinline__ float eluf(float x) { return x > 0.f ? x : expm1f(x); }

#define INV32767 (1.f / 32767.f)

// ---- per-graph node starts via binary search over sorted batch ----
__global__ void starts_k(const int* __restrict__ batch, int* __restrict__ starts) {
    int g = threadIdx.x;
    if (g > NG) return;
    int lo = 0, hi = NN;
    while (lo < hi) { int mid = (lo + hi) >> 1; if (batch[mid] < g) lo = mid + 1; else hi = mid; }
    starts[g] = lo;
}

// ---- coarse bucket histogram: 391 bins, LDS-staged, 153K global atomics ----
__global__ void __launch_bounds__(256) bcount_k(const int* __restrict__ ei,
                                                int* __restrict__ bcnt) {
    __shared__ int lh[NB];
    int tid = threadIdx.x;
    for (int i = tid; i < NB; i += 256) lh[i] = 0;
    __syncthreads();
    const int4* d4 = (const int4*)(ei + NE);
    int base4 = blockIdx.x * 2048;   // 8192 edges / 4
#pragma unroll
    for (int j = 0; j < 8; ++j) {
        int idx = base4 + j * 256 + tid;
        if (idx < NE / 4) {
            int4 d = d4[idx];
            atomicAdd(&lh[d.x >> BSH], 1);
            atomicAdd(&lh[d.y >> BSH], 1);
            atomicAdd(&lh[d.z >> BSH], 1);
            atomicAdd(&lh[d.w >> BSH], 1);
        }
    }
    __syncthreads();
    for (int i = tid; i < NB; i += 256)
        if (lh[i] > 0) atomicAdd(&bcnt[i], lh[i]);
}

// ---- scan of 391 bucket counts -> bbase (persist) + bcur (consumed) ----
__global__ void bscan_k(const int* __restrict__ bcnt, int* __restrict__ bbase,
                        int* __restrict__ bcur, int* __restrict__ offs) {
    __shared__ int s[512];
    int tid = threadIdx.x;
    int v = (tid < NB) ? bcnt[tid] : 0;
    s[tid] = v;
    __syncthreads();
    for (int d = 1; d < 512; d <<= 1) {
        int t = (tid >= (unsigned)d) ? s[tid - d] : 0;
        __syncthreads();
        s[tid] += t;
        __syncthreads();
    }
    if (tid < NB) {
        int e = s[tid] - v;   // exclusive
        bbase[tid] = e;
        bcur[tid] = e;
    }
    if (tid == 0) { bbase[NB] = NE; offs[NN] = NE; }
}

// ---- pass A: route edges into 391 dst-range buckets ----
__global__ void __launch_bounds__(256) passA(const int* __restrict__ ei,
        const float* __restrict__ ea, int* __restrict__ bcur,
        uint2* __restrict__ recsA) {
    __shared__ int lh[NB];
    __shared__ int gcur[NB];
    int tid = threadIdx.x;
    for (int i = tid; i < NB; i += 256) lh[i] = 0;
    __syncthreads();
    int base = blockIdx.x * 4096;
    uint2 rec[16];
    int bk[16];
#pragma unroll
    for (int j = 0; j < 16; ++j) {
        int e = base + j * 256 + tid;
        bk[j] = -1;
        if (e < NE) {
            int src = ei[e];
            int dst = ei[NE + e];
            float2 p = ((const float2*)ea)[e];
            unsigned q0 = (unsigned)__float2uint_rn(p.x * 32767.f);
            unsigned q1 = (unsigned)__float2uint_rn(p.y * 32767.f);
            rec[j] = make_uint2((unsigned)src | (q0 << 17), (unsigned)dst | (q1 << 17));
            bk[j] = dst >> BSH;
            atomicAdd(&lh[bk[j]], 1);
        }
    }
    __syncthreads();
    for (int i = tid; i < NB; i += 256)
        if (lh[i] > 0) gcur[i] = atomicAdd(&bcur[i], lh[i]);
    __syncthreads();
#pragma unroll
    for (int j = 0; j < 16; ++j) {
        if (bk[j] >= 0) {
            int pos = atomicAdd(&gcur[bk[j]], 1);
            recsA[pos] = rec[j];
        }
    }
}

// ---- fine pass: per-bucket LDS count + scan + scatter -> offs + recsB ----
// No global atomics at all; all placement arithmetic in LDS.
__global__ void __launch_bounds__(256) fine_k(const int* __restrict__ bbase,
        const uint2* __restrict__ recsA, int* __restrict__ offs,
        uint2* __restrict__ recsB) {
    __shared__ int cnt[256];
    __shared__ int sc[256];
    __shared__ int cur[256];
    int b = blockIdx.x;
    int tid = threadIdx.x;
    int rbeg = bbase[b], rend = bbase[b + 1];
    cnt[tid] = 0;
    __syncthreads();
    for (int i = rbeg + tid; i < rend; i += 256) {
        int d = (int)(recsA[i].y & 0x1FFFFu) & 255;
        atomicAdd(&cnt[d], 1);
    }
    __syncthreads();
    int v = cnt[tid];
    sc[tid] = v;
    __syncthreads();
    for (int d = 1; d < 256; d <<= 1) {
        int t = (tid >= (unsigned)d) ? sc[tid - d] : 0;
        __syncthreads();
        sc[tid] += t;
        __syncthreads();
    }
    int excl = sc[tid] - v;
    cur[tid] = excl;
    int node = (b << BSH) + tid;
    if (node < NN) offs[node] = rbeg + excl;
    __syncthreads();
    for (int i = rbeg + tid; i < rend; i += 256) {
        uint2 rc = recsA[i];
        int d = (int)(rc.y & 0x1FFFFu) & 255;
        int rank = atomicAdd(&cur[d], 1);
        recsB[rbeg + rank] = rc;
    }
}

// ---- conv1: gather per node, T[4][3] in regs, 12x16 GEMV ----
__global__ void __launch_bounds__(256) conv1_gather(const int* __restrict__ offs,
        const uint2* __restrict__ recs, const float* __restrict__ x,
        const float* __restrict__ W1, float* __restrict__ h1) {
    __shared__ float sW[192];
    if (threadIdx.x < 192) sW[threadIdx.x] = W1[threadIdx.x];
    __syncthreads();
    int n = blockIdx.x * blockDim.x + threadIdx.x;
    if (n >= NN) return;
    int off = offs[n], end = offs[n + 1];
    float T[12];
#pragma unroll
    for (int i = 0; i < 12; ++i) T[i] = 0.f;
    for (int e = off; e < end; ++e) {
        uint2 r = recs[e];
        int s = (int)(r.x & 0x1FFFFu);
        float p0 = (float)(r.x >> 17) * INV32767;
        float p1 = (float)(r.y >> 17) * INV32767;
        float b0 = (1.f - p1) * (1.f - p0), b1 = (1.f - p1) * p0;
        float b2 = p1 * (1.f - p0), b3 = p1 * p0;
        float x0 = x[3 * s], x1 = x[3 * s + 1], x2 = x[3 * s + 2];
        T[0] = fmaf(b0, x0, T[0]);  T[1] = fmaf(b0, x1, T[1]);  T[2]  = fmaf(b0, x2, T[2]);
        T[3] = fmaf(b1, x0, T[3]);  T[4] = fmaf(b1, x1, T[4]);  T[5]  = fmaf(b1, x2, T[5]);
        T[6] = fmaf(b2, x0, T[6]);  T[7] = fmaf(b2, x1, T[7]);  T[8]  = fmaf(b2, x2, T[8]);
        T[9] = fmaf(b3, x0, T[9]);  T[10]= fmaf(b3, x1, T[10]); T[11] = fmaf(b3, x2, T[11]);
    }
    float inv = 1.f / fmaxf((float)(end - off), 1.f);
    float ov[16];
#pragma unroll
    for (int o = 0; o < 16; ++o) {
        float acc = 0.f;
#pragma unroll
        for (int k = 0; k < 4; ++k)
#pragma unroll
            for (int i = 0; i < 3; ++i)
                acc = fmaf(T[k * 3 + i], sW[k * 48 + i * 16 + o], acc);
        acc *= inv;
        ov[o] = eluf(acc);
    }
    float4* hp = (float4*)(h1 + (long)n * 16);
#pragma unroll
    for (int q = 0; q < 4; ++q)
        hp[q] = make_float4(ov[4 * q], ov[4 * q + 1], ov[4 * q + 2], ov[4 * q + 3]);
}

// ---- BN stats: plain sum/sumsq over h (C channels) ----
template <int C>
__global__ void bn_sum(const float* __restrict__ h, float* __restrict__ st) {
    __shared__ float ss[C], sq[C];
    if (threadIdx.x < C) { ss[threadIdx.x] = 0.f; sq[threadIdx.x] = 0.f; }
    __syncthreads();
    const int total = NN * C;
    const int stride = gridDim.x * blockDim.x;
    float a = 0.f, q = 0.f;
    for (int i = blockIdx.x * blockDim.x + threadIdx.x; i < total; i += stride) {
        float v = h[i];
        a += v; q += v * v;
    }
#pragma unroll
    for (int d = C; d < 64; d <<= 1) { a += __shfl_xor(a, d); q += __shfl_xor(q, d); }
    int lane = threadIdx.x & 63;
    if (lane < C) { atomicAdd(&ss[lane], a); atomicAdd(&sq[lane], q); }
    __syncthreads();
    if (threadIdx.x < C) {
        atomAdd(&st[threadIdx.x], ss[threadIdx.x]);
        atomAdd(&st[C + threadIdx.x], sq[threadIdx.x]);
    }
}

// ---- conv2: gather per node, U[64]+S[4] in regs, 64x32 GEMV vs LDS W2' ----
__global__ void __launch_bounds__(256) conv2_gather(const int* __restrict__ offs,
        const uint2* __restrict__ recs, const float* __restrict__ h1,
        const float* __restrict__ st1, const float* __restrict__ g1,
        const float* __restrict__ b1v, const float* __restrict__ W2,
        float* __restrict__ h2) {
    __shared__ float s_sc[16], s_sh[16];
    __shared__ float sWp[2048];  // sc_i * W2[k][i][o]
    __shared__ float sV[128];    // sum_i sh_i * W2[k][i][o]
    if (threadIdx.x < 16) {
        int c = threadIdx.x;
        float mu = st1[c] * (1.f / NN);
        float var = st1[16 + c] * (1.f / NN) - mu * mu;
        float rs = rsqrtf(var + EPSF);
        float s = g1[c] * rs;
        s_sc[c] = s;
        s_sh[c] = b1v[c] - mu * s;
    }
    __syncthreads();
    for (int idx = threadIdx.x; idx < 2048; idx += blockDim.x) {
        int i = (idx & 511) >> 5;
        sWp[idx] = s_sc[i] * W2[idx];
    }
    if (threadIdx.x < 128) {
        int k = threadIdx.x >> 5, o = threadIdx.x & 31;
        float acc = 0.f;
#pragma unroll
        for (int i = 0; i < 16; ++i) acc = fmaf(s_sh[i], W2[k * 512 + i * 32 + o], acc);
        sV[threadIdx.x] = acc;
    }
    __syncthreads();
    int n = blockIdx.x * blockDim.x + threadIdx.x;
    if (n >= NN) return;
    int off = offs[n], end = offs[n + 1];
    float U[64];
    float S0 = 0.f, S1 = 0.f, S2 = 0.f, S3 = 0.f;
#pragma unroll
    for (int i = 0; i < 64; ++i) U[i] = 0.f;
    for (int e = off; e < end; ++e) {
        uint2 r = recs[e];
        int s = (int)(r.x & 0x1FFFFu);
        float p0 = (float)(r.x >> 17) * INV32767;
        float p1 = (float)(r.y >> 17) * INV32767;
        float b0 = (1.f - p1) * (1.f - p0), b1 = (1.f - p1) * p0;
        float b2 = p1 * (1.f - p0), b3 = p1 * p0;
        const float4* hp = (const float4*)(h1 + (long)s * 16);
        float4 t0 = hp[0], t1 = hp[1], t2 = hp[2], t3 = hp[3];
        float hv[16] = {t0.x, t0.y, t0.z, t0.w, t1.x, t1.y, t1.z, t1.w,
                        t2.x, t2.y, t2.z, t2.w, t3.x, t3.y, t3.z, t3.w};
#pragma unroll
        for (int i = 0; i < 16; ++i) {
            U[i]      = fmaf(b0, hv[i], U[i]);
            U[16 + i] = fmaf(b1, hv[i], U[16 + i]);
            U[32 + i] = fmaf(b2, hv[i], U[32 + i]);
            U[48 + i] = fmaf(b3, hv[i], U[48 + i]);
        }
        S0 += b0; S1 += b1; S2 += b2; S3 += b3;
    }
    float inv = 1.f / fmaxf((float)(end - off), 1.f);
    float4 acc[8];
#pragma unroll
    for (int ob = 0; ob < 8; ++ob) acc[ob] = make_float4(0.f, 0.f, 0.f, 0.f);
    const float4* Wp4 = (const float4*)sWp;
#pragma unroll 4
    for (int ki = 0; ki < 64; ++ki) {
        float u = U[ki];
#pragma unroll
        for (int ob = 0; ob < 8; ++ob) {
            float4 w = Wp4[ki * 8 + ob];
            acc[ob].x = fmaf(u, w.x, acc[ob].x);
            acc[ob].y = fmaf(u, w.y, acc[ob].y);
            acc[ob].z = fmaf(u, w.z, acc[ob].z);
            acc[ob].w = fmaf(u, w.w, acc[ob].w);
        }
    }
    const float4* V4 = (const float4*)sV;
    float Sarr[4] = {S0, S1, S2, S3};
#pragma unroll
    for (int k = 0; k < 4; ++k) {
        float u = Sarr[k];
#pragma unroll
        for (int ob = 0; ob < 8; ++ob) {
            float4 w = V4[k * 8 + ob];
            acc[ob].x = fmaf(u, w.x, acc[ob].x);
            acc[ob].y = fmaf(u, w.y, acc[ob].y);
            acc[ob].z = fmaf(u, w.z, acc[ob].z);
            acc[ob].w = fmaf(u, w.w, acc[ob].w);
        }
    }
    float4* out4 = (float4*)(h2 + (long)n * 32);
#pragma unroll
    for (int ob = 0; ob < 8; ++ob) {
        float4 a = acc[ob];
        a.x = eluf(a.x * inv); a.y = eluf(a.y * inv);
        a.z = eluf(a.z * inv); a.w = eluf(a.w * inv);
        out4[ob] = a;
    }
}

// ---- per-graph mean pool with BN2 affine, exploiting sorted batch ----
__global__ void pool_k(const float* __restrict__ h2pre, const float* __restrict__ st2,
                       const float* __restrict__ g2, const float* __restrict__ b2v,
                       const int* __restrict__ batch, float* __restrict__ gpool) {
    int t = blockIdx.x * blockDim.x + threadIdx.x;
    int c = t & 31;
    int chunk = t >> 5;
    if (chunk >= NN / 32) return;
    float mu = st2[c] * (1.f / NN);
    float var = st2[32 + c] * (1.f / NN) - mu * mu;
    float rs = rsqrtf(var + EPSF);
    float s = g2[c] * rs;
    float sh = b2v[c] - mu * s;
    int n0 = chunk * 32;
    int g_cur = batch[n0];
    float acc = 0.f;
    for (int i = 0; i < 32; ++i) {
        int n = n0 + i;
        int g = batch[n];
        float v = fmaf(h2pre[(long)n * 32 + c], s, sh);
        if (g != g_cur) {
            atomAdd(gpool + g_cur * 32 + c, acc);
            acc = 0.f;
            g_cur = g;
        }
        acc += v;
    }
    atomAdd(gpool + g_cur * 32 + c, acc);
}

// ---- final: gm = gpool/cnt ; out = gm @ fc^T ----
__global__ void final_k(const float* __restrict__ gpool, const int* __restrict__ starts,
                        const float* __restrict__ fc, float* __restrict__ out) {
    int t = blockIdx.x * blockDim.x + threadIdx.x;
    if (t >= NG * 10) return;
    int g = t / 10, j = t - g * 10;
    float cg = (float)(starts[g + 1] - starts[g]);
    float inv = 1.f / fmaxf(cg, 1.f);
    float sv = 0.f;
#pragma unroll
    for (int ch = 0; ch < 32; ++ch) sv = fmaf(gpool[g * 32 + ch], fc[j * 32 + ch], sv);
    out[t] = sv * inv;
}

extern "C" void kernel_launch(void* const* d_in, const int* in_sizes, int n_in,
                              void* d_out, int out_size, void* d_ws, size_t ws_size,
                              hipStream_t stream) {
    const float* x     = (const float*)d_in[0];
    const int*   ei    = (const int*)d_in[1];
    const float* ea    = (const float*)d_in[2];
    const int*   batch = (const int*)d_in[3];
    const float* W1    = (const float*)d_in[4];
    const float* g1    = (const float*)d_in[5];
    const float* b1v   = (const float*)d_in[6];
    const float* W2    = (const float*)d_in[7];
    const float* g2    = (const float*)d_in[8];
    const float* b2v   = (const float*)d_in[9];
    const float* fc    = (const float*)d_in[10];
    float* ws = (float*)d_ws;

    float*  st1    = ws + OFF_ST1;
    float*  st2    = ws + OFF_ST2;
    float*  gpool  = ws + OFF_GPOOL;
    int*    bcnt   = (int*)(ws + OFF_BCNT);
    int*    bbase  = (int*)(ws + OFF_BBASE);
    int*    bcur   = (int*)(ws + OFF_BCUR);
    int*    offs   = (int*)(ws + OFF_OFFS);
    int*    starts = (int*)(ws + OFF_STARTS);
    float*  h1     = ws + OFF_H1;
    float*  h2     = ws + OFF_H2;
    uint2*  recsA  = (uint2*)(ws + OFF_RECSA);
    uint2*  recsB  = (uint2*)(ws + OFF_RECSB);

    hipMemsetAsync(ws, 0, (size_t)ZERO_FLOATS * sizeof(float), stream);
    starts_k<<<1, 128, 0, stream>>>(batch, starts);

    const int BLK = 256;
    const int NGRID = (NN + BLK - 1) / BLK;   // 391

    bcount_k<<<391, BLK, 0, stream>>>(ei, bcnt);
    bscan_k<<<1, 512, 0, stream>>>(bcnt, bbase, bcur, offs);
    passA<<<(NE + 4095) / 4096, BLK, 0, stream>>>(ei, ea, bcur, recsA);
    fine_k<<<NB, BLK, 0, stream>>>(bbase, recsA, offs, recsB);
    conv1_gather<<<NGRID, BLK, 0, stream>>>(offs, recsB, x, W1, h1);
    bn_sum<16><<<512, BLK, 0, stream>>>(h1, st1);
    conv2_gather<<<NGRID, BLK, 0, stream>>>(offs, recsB, h1, st1, g1, b1v, W2, h2);
    bn_sum<32><<<512, BLK, 0, stream>>>(h2, st2);
    pool_k<<<NGRID, BLK, 0, stream>>>(h2, st2, g2, b2v, batch, gpool);
    final_k<<<3, BLK, 0, stream>>>(gpool, starts, fc, (float*)d_out);
}

// Round 9
// 376.022 us; speedup vs baseline: 21.9462x; 1.0140x over previous
//
#include <hip/hip_runtime.h>
#include <hip/hip_fp16.h>
#include <math.h>

#define NN 100000
#define NE 3200000
#define NG 64
#define EPSF 1e-5f
#define NB 391       // buckets of 256 nodes: ceil(100000/256)
#define BSH 8        // bucket = dst >> 8

// ---- workspace layout (float offsets) ----
#define OFF_ST1     0          // 16 sum + 16 sumsq
#define OFF_ST2     32         // 32 sum + 32 sumsq
#define OFF_GPOOL   96         // 64*32
#define OFF_BCNT    2144       // int[392]
#define ZERO_FLOATS 2536       // everything above memset to 0
#define OFF_BBASE   2536       // int[392]
#define OFF_BCUR    2928       // int[392]
#define OFF_OFFS    3320       // int[100001] (+pad)
#define OFF_STARTS  103324     // int[65] (+pad)
#define OFF_H1      103392     // __half[100000*16] = 800000 floats (%4==0)
#define OFF_H2      903392     // float[100000*32] (%4==0)
#define OFF_RECSA   4103392    // uint2[3200000] (%4==0)
#define OFF_RECSB   10503392   // uint2[3200000] (%4==0)
// total ~16.9M floats = 67.6 MB

__device__ __forceinline__ void atomAdd(float* p, float v) {
#if defined(__gfx90a__) || defined(__gfx940__) || defined(__gfx941__) || defined(__gfx942__) || defined(__gfx950__)
    unsafeAtomicAdd(p, v);
#else
    atomicAdd(p, v);
#endif
}

__device__ __forceinline__ float eluf(float x) { return x > 0.f ? x : expm1f(x); }

#define INV32767 (1.f / 32767.f)

// ---- per-graph node starts via binary search over sorted batch ----
__global__ void starts_k(const int* __restrict__ batch, int* __restrict__ starts) {
    int g = threadIdx.x;
    if (g > NG) return;
    int lo = 0, hi = NN;
    while (lo < hi) { int mid = (lo + hi) >> 1; if (batch[mid] < g) lo = mid + 1; else hi = mid; }
    starts[g] = lo;
}

// ---- coarse bucket histogram: 391 bins, LDS-staged ----
__global__ void __launch_bounds__(256) bcount_k(const int* __restrict__ ei,
                                                int* __restrict__ bcnt) {
    __shared__ int lh[NB];
    int tid = threadIdx.x;
    for (int i = tid; i < NB; i += 256) lh[i] = 0;
    __syncthreads();
    const int4* d4 = (const int4*)(ei + NE);
    int base4 = blockIdx.x * 2048;   // 8192 edges / 4
#pragma unroll
    for (int j = 0; j < 8; ++j) {
        int idx = base4 + j * 256 + tid;
        if (idx < NE / 4) {
            int4 d = d4[idx];
            atomicAdd(&lh[d.x >> BSH], 1);
            atomicAdd(&lh[d.y >> BSH], 1);
            atomicAdd(&lh[d.z >> BSH], 1);
            atomicAdd(&lh[d.w >> BSH], 1);
        }
    }
    __syncthreads();
    for (int i = tid; i < NB; i += 256)
        if (lh[i] > 0) atomicAdd(&bcnt[i], lh[i]);
}

// ---- scan of 391 bucket counts -> bbase (persist) + bcur (consumed) ----
__global__ void bscan_k(const int* __restrict__ bcnt, int* __restrict__ bbase,
                        int* __restrict__ bcur, int* __restrict__ offs) {
    __shared__ int s[512];
    int tid = threadIdx.x;
    int v = (tid < NB) ? bcnt[tid] : 0;
    s[tid] = v;
    __syncthreads();
    for (int d = 1; d < 512; d <<= 1) {
        int t = (tid >= (unsigned)d) ? s[tid - d] : 0;
        __syncthreads();
        s[tid] += t;
        __syncthreads();
    }
    if (tid < NB) {
        int e = s[tid] - v;   // exclusive
        bbase[tid] = e;
        bcur[tid] = e;
    }
    if (tid == 0) { bbase[NB] = NE; offs[NN] = NE; }
}

// ---- pass A: route edges into 391 dst-range buckets ----
__global__ void __launch_bounds__(256) passA(const int* __restrict__ ei,
        const float* __restrict__ ea, int* __restrict__ bcur,
        uint2* __restrict__ recsA) {
    __shared__ int lh[NB];
    __shared__ int gcur[NB];
    int tid = threadIdx.x;
    for (int i = tid; i < NB; i += 256) lh[i] = 0;
    __syncthreads();
    int base = blockIdx.x * 4096;
    uint2 rec[16];
    int bk[16];
#pragma unroll
    for (int j = 0; j < 16; ++j) {
        int e = base + j * 256 + tid;
        bk[j] = -1;
        if (e < NE) {
            int src = ei[e];
            int dst = ei[NE + e];
            float2 p = ((const float2*)ea)[e];
            unsigned q0 = (unsigned)__float2uint_rn(p.x * 32767.f);
            unsigned q1 = (unsigned)__float2uint_rn(p.y * 32767.f);
            rec[j] = make_uint2((unsigned)src | (q0 << 17), (unsigned)dst | (q1 << 17));
            bk[j] = dst >> BSH;
            atomicAdd(&lh[bk[j]], 1);
        }
    }
    __syncthreads();
    for (int i = tid; i < NB; i += 256)
        if (lh[i] > 0) gcur[i] = atomicAdd(&bcur[i], lh[i]);
    __syncthreads();
#pragma unroll
    for (int j = 0; j < 16; ++j) {
        if (bk[j] >= 0) {
            int pos = atomicAdd(&gcur[bk[j]], 1);
            recsA[pos] = rec[j];
        }
    }
}

// ---- fine pass: per-bucket LDS count + scan + scatter -> offs + recsB ----
__global__ void __launch_bounds__(256) fine_k(const int* __restrict__ bbase,
        const uint2* __restrict__ recsA, int* __restrict__ offs,
        uint2* __restrict__ recsB) {
    __shared__ int cnt[256];
    __shared__ int sc[256];
    __shared__ int cur[256];
    int b = blockIdx.x;
    int tid = threadIdx.x;
    int rbeg = bbase[b], rend = bbase[b + 1];
    cnt[tid] = 0;
    __syncthreads();
    for (int i = rbeg + tid; i < rend; i += 256) {
        int d = (int)(recsA[i].y & 0x1FFFFu) & 255;
        atomicAdd(&cnt[d], 1);
    }
    __syncthreads();
    int v = cnt[tid];
    sc[tid] = v;
    __syncthreads();
    for (int d = 1; d < 256; d <<= 1) {
        int t = (tid >= (unsigned)d) ? sc[tid - d] : 0;
        __syncthreads();
        sc[tid] += t;
        __syncthreads();
    }
    int excl = sc[tid] - v;
    cur[tid] = excl;
    int node = (b << BSH) + tid;
    if (node < NN) offs[node] = rbeg + excl;
    __syncthreads();
    for (int i = rbeg + tid; i < rend; i += 256) {
        uint2 rc = recsA[i];
        int d = (int)(rc.y & 0x1FFFFu) & 255;
        int rank = atomicAdd(&cur[d], 1);
        recsB[rbeg + rank] = rc;
    }
}

// ---- conv1: 4 threads/node, partial T, partial GEMV, shfl-reduce, fp16 out ----
__global__ void __launch_bounds__(256) conv1_gather(const int* __restrict__ offs,
        const uint2* __restrict__ recs, const float* __restrict__ x,
        const float* __restrict__ W1, __half* __restrict__ h1) {
    __shared__ float sW[192];
    if (threadIdx.x < 192) sW[threadIdx.x] = W1[threadIdx.x];
    __syncthreads();
    int t = blockIdx.x * blockDim.x + threadIdx.x;
    int n = t >> 2, sub = t & 3;
    if (n >= NN) return;
    int off = offs[n], end = offs[n + 1];
    float T[12];
#pragma unroll
    for (int i = 0; i < 12; ++i) T[i] = 0.f;
    for (int e = off + sub; e < end; e += 4) {
        uint2 r = recs[e];
        int s = (int)(r.x & 0x1FFFFu);
        float p0 = (float)(r.x >> 17) * INV32767;
        float p1 = (float)(r.y >> 17) * INV32767;
        float b0 = (1.f - p1) * (1.f - p0), b1 = (1.f - p1) * p0;
        float b2 = p1 * (1.f - p0), b3 = p1 * p0;
        float x0 = x[3 * s], x1 = x[3 * s + 1], x2 = x[3 * s + 2];
        T[0] = fmaf(b0, x0, T[0]);  T[1] = fmaf(b0, x1, T[1]);  T[2]  = fmaf(b0, x2, T[2]);
        T[3] = fmaf(b1, x0, T[3]);  T[4] = fmaf(b1, x1, T[4]);  T[5]  = fmaf(b1, x2, T[5]);
        T[6] = fmaf(b2, x0, T[6]);  T[7] = fmaf(b2, x1, T[7]);  T[8]  = fmaf(b2, x2, T[8]);
        T[9] = fmaf(b3, x0, T[9]);  T[10]= fmaf(b3, x1, T[10]); T[11] = fmaf(b3, x2, T[11]);
    }
    float ov[16];
#pragma unroll
    for (int o = 0; o < 16; ++o) {
        float acc = 0.f;
#pragma unroll
        for (int k = 0; k < 4; ++k)
#pragma unroll
            for (int i = 0; i < 3; ++i)
                acc = fmaf(T[k * 3 + i], sW[k * 48 + i * 16 + o], acc);
        acc += __shfl_xor(acc, 1);
        acc += __shfl_xor(acc, 2);
        ov[o] = acc;
    }
    if (sub != 0) return;
    float inv = 1.f / fmaxf((float)(end - off), 1.f);
    __half2 hh[8];
#pragma unroll
    for (int q = 0; q < 8; ++q)
        hh[q] = __float22half2_rn(make_float2(eluf(ov[2 * q] * inv),
                                              eluf(ov[2 * q + 1] * inv)));
    uint4* hp = (uint4*)(h1 + (long)n * 16);
    hp[0] = *(uint4*)&hh[0];
    hp[1] = *(uint4*)&hh[4];
}

// ---- BN1 stats from fp16 h1 ----
__global__ void bn_sum16h(const __half2* __restrict__ h, float* __restrict__ st) {
    __shared__ float ss[16], sq[16];
    if (threadIdx.x < 16) { ss[threadIdx.x] = 0.f; sq[threadIdx.x] = 0.f; }
    __syncthreads();
    const int total = NN * 8;                 // half2 elements
    const int stride = gridDim.x * blockDim.x; // multiple of 8
    float a0 = 0.f, a1 = 0.f, q0 = 0.f, q1 = 0.f;
    for (int i = blockIdx.x * blockDim.x + threadIdx.x; i < total; i += stride) {
        float2 f = __half22float2(h[i]);
        a0 += f.x; q0 += f.x * f.x;
        a1 += f.y; q1 += f.y * f.y;
    }
#pragma unroll
    for (int d = 8; d < 64; d <<= 1) {
        a0 += __shfl_xor(a0, d); q0 += __shfl_xor(q0, d);
        a1 += __shfl_xor(a1, d); q1 += __shfl_xor(q1, d);
    }
    int lane = threadIdx.x & 63;
    if (lane < 8) {
        atomicAdd(&ss[2 * lane], a0);     atomicAdd(&sq[2 * lane], q0);
        atomicAdd(&ss[2 * lane + 1], a1); atomicAdd(&sq[2 * lane + 1], q1);
    }
    __syncthreads();
    if (threadIdx.x < 16) {
        atomAdd(&st[threadIdx.x], ss[threadIdx.x]);
        atomAdd(&st[16 + threadIdx.x], sq[threadIdx.x]);
    }
}

// ---- BN2 stats over f32 h2 ----
__global__ void bn_sum32(const float* __restrict__ h, float* __restrict__ st) {
    __shared__ float ss[32], sq[32];
    if (threadIdx.x < 32) { ss[threadIdx.x] = 0.f; sq[threadIdx.x] = 0.f; }
    __syncthreads();
    const int total = NN * 32;
    const int stride = gridDim.x * blockDim.x;
    float a = 0.f, q = 0.f;
    for (int i = blockIdx.x * blockDim.x + threadIdx.x; i < total; i += stride) {
        float v = h[i];
        a += v; q += v * v;
    }
    a += __shfl_xor(a, 32);
    q += __shfl_xor(q, 32);
    int lane = threadIdx.x & 63;
    if (lane < 32) { atomicAdd(&ss[lane], a); atomicAdd(&sq[lane], q); }
    __syncthreads();
    if (threadIdx.x < 32) {
        atomAdd(&st[threadIdx.x], ss[threadIdx.x]);
        atomAdd(&st[32 + threadIdx.x], sq[threadIdx.x]);
    }
}

// ---- conv2: 4 threads/node, fp16 h1 gather (L2-resident), shfl-reduce ----
__global__ void __launch_bounds__(256) conv2_gather(const int* __restrict__ offs,
        const uint2* __restrict__ recs, const __half* __restrict__ h1,
        const float* __restrict__ st1, const float* __restrict__ g1,
        const float* __restrict__ b1v, const float* __restrict__ W2,
        float* __restrict__ h2) {
    __shared__ float s_sc[16], s_sh[16];
    __shared__ float sWp[2048];  // sc_i * W2[k][i][o]
    __shared__ float sV[128];    // sum_i sh_i * W2[k][i][o]
    if (threadIdx.x < 16) {
        int c = threadIdx.x;
        float mu = st1[c] * (1.f / NN);
        float var = st1[16 + c] * (1.f / NN) - mu * mu;
        float rs = rsqrtf(var + EPSF);
        float s = g1[c] * rs;
        s_sc[c] = s;
        s_sh[c] = b1v[c] - mu * s;
    }
    __syncthreads();
    for (int idx = threadIdx.x; idx < 2048; idx += blockDim.x) {
        int i = (idx & 511) >> 5;
        sWp[idx] = s_sc[i] * W2[idx];
    }
    if (threadIdx.x < 128) {
        int k = threadIdx.x >> 5, o = threadIdx.x & 31;
        float acc = 0.f;
#pragma unroll
        for (int i = 0; i < 16; ++i) acc = fmaf(s_sh[i], W2[k * 512 + i * 32 + o], acc);
        sV[threadIdx.x] = acc;
    }
    __syncthreads();
    int t = blockIdx.x * blockDim.x + threadIdx.x;
    int n = t >> 2, sub = t & 3;
    if (n >= NN) return;
    int off = offs[n], end = offs[n + 1];
    float U[64];
    float S0 = 0.f, S1 = 0.f, S2 = 0.f, S3 = 0.f;
#pragma unroll
    for (int i = 0; i < 64; ++i) U[i] = 0.f;
    for (int e = off + sub; e < end; e += 4) {
        uint2 r = recs[e];
        int s = (int)(r.x & 0x1FFFFu);
        float p0 = (float)(r.x >> 17) * INV32767;
        float p1 = (float)(r.y >> 17) * INV32767;
        float b0 = (1.f - p1) * (1.f - p0), b1 = (1.f - p1) * p0;
        float b2 = p1 * (1.f - p0), b3 = p1 * p0;
        const uint4* hp = (const uint4*)(h1 + (long)s * 16);
        uint4 ua = hp[0], ub = hp[1];
        float2 f0 = __half22float2(*(const __half2*)&ua.x);
        float2 f1 = __half22float2(*(const __half2*)&ua.y);
        float2 f2 = __half22float2(*(const __half2*)&ua.z);
        float2 f3 = __half22float2(*(const __half2*)&ua.w);
        float2 f4 = __half22float2(*(const __half2*)&ub.x);
        float2 f5 = __half22float2(*(const __half2*)&ub.y);
        float2 f6 = __half22float2(*(const __half2*)&ub.z);
        float2 f7 = __half22float2(*(const __half2*)&ub.w);
        float hv[16] = {f0.x, f0.y, f1.x, f1.y, f2.x, f2.y, f3.x, f3.y,
                        f4.x, f4.y, f5.x, f5.y, f6.x, f6.y, f7.x, f7.y};
#pragma unroll
        for (int i = 0; i < 16; ++i) {
            U[i]      = fmaf(b0, hv[i], U[i]);
            U[16 + i] = fmaf(b1, hv[i], U[16 + i]);
            U[32 + i] = fmaf(b2, hv[i], U[32 + i]);
            U[48 + i] = fmaf(b3, hv[i], U[48 + i]);
        }
        S0 += b0; S1 += b1; S2 += b2; S3 += b3;
    }
    float4 acc[8];
#pragma unroll
    for (int ob = 0; ob < 8; ++ob) acc[ob] = make_float4(0.f, 0.f, 0.f, 0.f);
    const float4* Wp4 = (const float4*)sWp;
#pragma unroll 4
    for (int ki = 0; ki < 64; ++ki) {
        float u = U[ki];
#pragma unroll
        for (int ob = 0; ob < 8; ++ob) {
            float4 w = Wp4[ki * 8 + ob];
            acc[ob].x = fmaf(u, w.x, acc[ob].x);
            acc[ob].y = fmaf(u, w.y, acc[ob].y);
            acc[ob].z = fmaf(u, w.z, acc[ob].z);
            acc[ob].w = fmaf(u, w.w, acc[ob].w);
        }
    }
    const float4* V4 = (const float4*)sV;
    float Sarr[4] = {S0, S1, S2, S3};
#pragma unroll
    for (int k = 0; k < 4; ++k) {
        float u = Sarr[k];
#pragma unroll
        for (int ob = 0; ob < 8; ++ob) {
            float4 w = V4[k * 8 + ob];
            acc[ob].x = fmaf(u, w.x, acc[ob].x);
            acc[ob].y = fmaf(u, w.y, acc[ob].y);
            acc[ob].z = fmaf(u, w.z, acc[ob].z);
            acc[ob].w = fmaf(u, w.w, acc[ob].w);
        }
    }
    // reduce partial acc across the 4 sub-lanes
#pragma unroll
    for (int ob = 0; ob < 8; ++ob) {
        acc[ob].x += __shfl_xor(acc[ob].x, 1); acc[ob].x += __shfl_xor(acc[ob].x, 2);
        acc[ob].y += __shfl_xor(acc[ob].y, 1); acc[ob].y += __shfl_xor(acc[ob].y, 2);
        acc[ob].z += __shfl_xor(acc[ob].z, 1); acc[ob].z += __shfl_xor(acc[ob].z, 2);
        acc[ob].w += __shfl_xor(acc[ob].w, 1); acc[ob].w += __shfl_xor(acc[ob].w, 2);
    }
    if (sub != 0) return;
    float inv = 1.f / fmaxf((float)(end - off), 1.f);
    float4* out4 = (float4*)(h2 + (long)n * 32);
#pragma unroll
    for (int ob = 0; ob < 8; ++ob) {
        float4 a = acc[ob];
        a.x = eluf(a.x * inv); a.y = eluf(a.y * inv);
        a.z = eluf(a.z * inv); a.w = eluf(a.w * inv);
        out4[ob] = a;
    }
}

// ---- per-graph mean pool with BN2 affine, exploiting sorted batch ----
__global__ void pool_k(const float* __restrict__ h2pre, const float* __restrict__ st2,
                       const float* __restrict__ g2, const float* __restrict__ b2v,
                       const int* __restrict__ batch, float* __restrict__ gpool) {
    int t = blockIdx.x * blockDim.x + threadIdx.x;
    int c = t & 31;
    int chunk = t >> 5;
    if (chunk >= NN / 32) return;
    float mu = st2[c] * (1.f / NN);
    float var = st2[32 + c] * (1.f / NN) - mu * mu;
    float rs = rsqrtf(var + EPSF);
    float s = g2[c] * rs;
    float sh = b2v[c] - mu * s;
    int n0 = chunk * 32;
    int g_cur = batch[n0];
    float acc = 0.f;
    for (int i = 0; i < 32; ++i) {
        int n = n0 + i;
        int g = batch[n];
        float v = fmaf(h2pre[(long)n * 32 + c], s, sh);
        if (g != g_cur) {
            atomAdd(gpool + g_cur * 32 + c, acc);
            acc = 0.f;
            g_cur = g;
        }
        acc += v;
    }
    atomAdd(gpool + g_cur * 32 + c, acc);
}

// ---- final: gm = gpool/cnt ; out = gm @ fc^T ----
__global__ void final_k(const float* __restrict__ gpool, const int* __restrict__ starts,
                        const float* __restrict__ fc, float* __restrict__ out) {
    int t = blockIdx.x * blockDim.x + threadIdx.x;
    if (t >= NG * 10) return;
    int g = t / 10, j = t - g * 10;
    float cg = (float)(starts[g + 1] - starts[g]);
    float inv = 1.f / fmaxf(cg, 1.f);
    float sv = 0.f;
#pragma unroll
    for (int ch = 0; ch < 32; ++ch) sv = fmaf(gpool[g * 32 + ch], fc[j * 32 + ch], sv);
    out[t] = sv * inv;
}

extern "C" void kernel_launch(void* const* d_in, const int* in_sizes, int n_in,
                              void* d_out, int out_size, void* d_ws, size_t ws_size,
                              hipStream_t stream) {
    const float* x     = (const float*)d_in[0];
    const int*   ei    = (const int*)d_in[1];
    const float* ea    = (const float*)d_in[2];
    const int*   batch = (const int*)d_in[3];
    const float* W1    = (const float*)d_in[4];
    const float* g1    = (const float*)d_in[5];
    const float* b1v   = (const float*)d_in[6];
    const float* W2    = (const float*)d_in[7];
    const float* g2    = (const float*)d_in[8];
    const float* b2v   = (const float*)d_in[9];
    const float* fc    = (const float*)d_in[10];
    float* ws = (float*)d_ws;

    float*  st1    = ws + OFF_ST1;
    float*  st2    = ws + OFF_ST2;
    float*  gpool  = ws + OFF_GPOOL;
    int*    bcnt   = (int*)(ws + OFF_BCNT);
    int*    bbase  = (int*)(ws + OFF_BBASE);
    int*    bcur   = (int*)(ws + OFF_BCUR);
    int*    offs   = (int*)(ws + OFF_OFFS);
    int*    starts = (int*)(ws + OFF_STARTS);
    __half* h1     = (__half*)(ws + OFF_H1);
    float*  h2     = ws + OFF_H2;
    uint2*  recsA  = (uint2*)(ws + OFF_RECSA);
    uint2*  recsB  = (uint2*)(ws + OFF_RECSB);

    hipMemsetAsync(ws, 0, (size_t)ZERO_FLOATS * sizeof(float), stream);
    starts_k<<<1, 128, 0, stream>>>(batch, starts);

    const int BLK = 256;
    const int NGRID4 = (NN * 4 + BLK - 1) / BLK;   // 1563

    bcount_k<<<391, BLK, 0, stream>>>(ei, bcnt);
    bscan_k<<<1, 512, 0, stream>>>(bcnt, bbase, bcur, offs);
    passA<<<(NE + 4095) / 4096, BLK, 0, stream>>>(ei, ea, bcur, recsA);
    fine_k<<<NB, BLK, 0, stream>>>(bbase, recsA, offs, recsB);
    conv1_gather<<<NGRID4, BLK, 0, stream>>>(offs, recsB, x, W1, h1);
    bn_sum16h<<<512, BLK, 0, stream>>>((const __half2*)h1, st1);
    conv2_gather<<<NGRID4, BLK, 0, stream>>>(offs, recsB, h1, st1, g1, b1v, W2, h2);
    bn_sum32<<<512, BLK, 0, stream>>>(h2, st2);
    pool_k<<<(NN + BLK - 1) / BLK, BLK, 0, stream>>>(h2, st2, g2, b2v, batch, gpool);
    final_k<<<3, BLK, 0, stream>>>(gpool, starts, fc, (float*)d_out);
}

// Round 10
// 354.598 us; speedup vs baseline: 23.2721x; 1.0604x over previous
//
#include <hip/hip_runtime.h>
#include <hip/hip_fp16.h>
#include <math.h>

#define NN 100000
#define NE 3200000
#define NG 64
#define EPSF 1e-5f
#define NB 391       // buckets of 256 nodes: ceil(100000/256)
#define BSH 8        // bucket = dst >> 8

// ---- workspace layout (float offsets) ----
#define OFF_ST1     0          // 16 sum + 16 sumsq
#define OFF_ST2     32         // 32 sum + 32 sumsq
#define OFF_GPOOL   96         // 64*32
#define OFF_BCNT    2144       // int[392]
#define ZERO_FLOATS 2536       // everything above memset to 0
#define OFF_BBASE   2536       // int[392]
#define OFF_BCUR    2928       // int[392]
#define OFF_OFFS    3320       // int[100001] (+pad)
#define OFF_STARTS  103324     // int[65] (+pad)
#define OFF_H1      103392     // __half[100000*16] = 800000 floats (%4==0)
#define OFF_H2      903392     // float[100000*32] (%4==0)
#define OFF_RECSA   4103392    // uint2[3200000] (%4==0)
#define OFF_RECSB   10503392   // uint2[3200000] (%4==0)
// total ~16.9M floats = 67.6 MB

__device__ __forceinline__ void atomAdd(float* p, float v) {
#if defined(__gfx90a__) || defined(__gfx940__) || defined(__gfx941__) || defined(__gfx942__) || defined(__gfx950__)
    unsafeAtomicAdd(p, v);
#else
    atomicAdd(p, v);
#endif
}

__device__ __forceinline__ float eluf(float x) { return x > 0.f ? x : expm1f(x); }

#define INV32767 (1.f / 32767.f)

// ---- per-graph node starts via binary search over sorted batch ----
__global__ void starts_k(const int* __restrict__ batch, int* __restrict__ starts) {
    int g = threadIdx.x;
    if (g > NG) return;
    int lo = 0, hi = NN;
    while (lo < hi) { int mid = (lo + hi) >> 1; if (batch[mid] < g) lo = mid + 1; else hi = mid; }
    starts[g] = lo;
}

// ---- coarse bucket histogram: 391 bins, LDS-staged ----
__global__ void __launch_bounds__(256) bcount_k(const int* __restrict__ ei,
                                                int* __restrict__ bcnt) {
    __shared__ int lh[NB];
    int tid = threadIdx.x;
    for (int i = tid; i < NB; i += 256) lh[i] = 0;
    __syncthreads();
    const int4* d4 = (const int4*)(ei + NE);
    int base4 = blockIdx.x * 2048;   // 8192 edges / 4
#pragma unroll
    for (int j = 0; j < 8; ++j) {
        int idx = base4 + j * 256 + tid;
        if (idx < NE / 4) {
            int4 d = d4[idx];
            atomicAdd(&lh[d.x >> BSH], 1);
            atomicAdd(&lh[d.y >> BSH], 1);
            atomicAdd(&lh[d.z >> BSH], 1);
            atomicAdd(&lh[d.w >> BSH], 1);
        }
    }
    __syncthreads();
    for (int i = tid; i < NB; i += 256)
        if (lh[i] > 0) atomicAdd(&bcnt[i], lh[i]);
}

// ---- scan of 391 bucket counts -> bbase (persist) + bcur (consumed) ----
__global__ void bscan_k(const int* __restrict__ bcnt, int* __restrict__ bbase,
                        int* __restrict__ bcur, int* __restrict__ offs) {
    __shared__ int s[512];
    int tid = threadIdx.x;
    int v = (tid < NB) ? bcnt[tid] : 0;
    s[tid] = v;
    __syncthreads();
    for (int d = 1; d < 512; d <<= 1) {
        int t = (tid >= (unsigned)d) ? s[tid - d] : 0;
        __syncthreads();
        s[tid] += t;
        __syncthreads();
    }
    if (tid < NB) {
        int e = s[tid] - v;   // exclusive
        bbase[tid] = e;
        bcur[tid] = e;
    }
    if (tid == 0) { bbase[NB] = NE; offs[NN] = NE; }
}

// ---- pass A: route edges into 391 dst-range buckets ----
__global__ void __launch_bounds__(256) passA(const int* __restrict__ ei,
        const float* __restrict__ ea, int* __restrict__ bcur,
        uint2* __restrict__ recsA) {
    __shared__ int lh[NB];
    __shared__ int gcur[NB];
    int tid = threadIdx.x;
    for (int i = tid; i < NB; i += 256) lh[i] = 0;
    __syncthreads();
    int base = blockIdx.x * 4096;
    uint2 rec[16];
    int bk[16];
#pragma unroll
    for (int j = 0; j < 16; ++j) {
        int e = base + j * 256 + tid;
        bk[j] = -1;
        if (e < NE) {
            int src = ei[e];
            int dst = ei[NE + e];
            float2 p = ((const float2*)ea)[e];
            unsigned q0 = (unsigned)__float2uint_rn(p.x * 32767.f);
            unsigned q1 = (unsigned)__float2uint_rn(p.y * 32767.f);
            rec[j] = make_uint2((unsigned)src | (q0 << 17), (unsigned)dst | (q1 << 17));
            bk[j] = dst >> BSH;
            atomicAdd(&lh[bk[j]], 1);
        }
    }
    __syncthreads();
    for (int i = tid; i < NB; i += 256)
        if (lh[i] > 0) gcur[i] = atomicAdd(&bcur[i], lh[i]);
    __syncthreads();
#pragma unroll
    for (int j = 0; j < 16; ++j) {
        if (bk[j] >= 0) {
            int pos = atomicAdd(&gcur[bk[j]], 1);
            recsA[pos] = rec[j];
        }
    }
}

// ---- fine pass: per-bucket LDS count + scan + scatter -> offs + recsB ----
__global__ void __launch_bounds__(256) fine_k(const int* __restrict__ bbase,
        const uint2* __restrict__ recsA, int* __restrict__ offs,
        uint2* __restrict__ recsB) {
    __shared__ int cnt[256];
    __shared__ int sc[256];
    __shared__ int cur[256];
    int b = blockIdx.x;
    int tid = threadIdx.x;
    int rbeg = bbase[b], rend = bbase[b + 1];
    cnt[tid] = 0;
    __syncthreads();
    for (int i = rbeg + tid; i < rend; i += 256) {
        int d = (int)(recsA[i].y & 0x1FFFFu) & 255;
        atomicAdd(&cnt[d], 1);
    }
    __syncthreads();
    int v = cnt[tid];
    sc[tid] = v;
    __syncthreads();
    for (int d = 1; d < 256; d <<= 1) {
        int t = (tid >= (unsigned)d) ? sc[tid - d] : 0;
        __syncthreads();
        sc[tid] += t;
        __syncthreads();
    }
    int excl = sc[tid] - v;
    cur[tid] = excl;
    int node = (b << BSH) + tid;
    if (node < NN) offs[node] = rbeg + excl;
    __syncthreads();
    for (int i = rbeg + tid; i < rend; i += 256) {
        uint2 rc = recsA[i];
        int d = (int)(rc.y & 0x1FFFFu) & 255;
        int rank = atomicAdd(&cur[d], 1);
        recsB[rbeg + rank] = rc;
    }
}

// ---- conv1: 4 threads/node, partial T, partial GEMV, shfl-reduce, fp16 out ----
__global__ void __launch_bounds__(256) conv1_gather(const int* __restrict__ offs,
        const uint2* __restrict__ recs, const float* __restrict__ x,
        const float* __restrict__ W1, __half* __restrict__ h1) {
    __shared__ float sW[192];
    if (threadIdx.x < 192) sW[threadIdx.x] = W1[threadIdx.x];
    __syncthreads();
    int t = blockIdx.x * blockDim.x + threadIdx.x;
    int n = t >> 2, sub = t & 3;
    if (n >= NN) return;
    int off = offs[n], end = offs[n + 1];
    float T[12];
#pragma unroll
    for (int i = 0; i < 12; ++i) T[i] = 0.f;
    for (int e = off + sub; e < end; e += 4) {
        uint2 r = recs[e];
        int s = (int)(r.x & 0x1FFFFu);
        float p0 = (float)(r.x >> 17) * INV32767;
        float p1 = (float)(r.y >> 17) * INV32767;
        float b0 = (1.f - p1) * (1.f - p0), b1 = (1.f - p1) * p0;
        float b2 = p1 * (1.f - p0), b3 = p1 * p0;
        float x0 = x[3 * s], x1 = x[3 * s + 1], x2 = x[3 * s + 2];
        T[0] = fmaf(b0, x0, T[0]);  T[1] = fmaf(b0, x1, T[1]);  T[2]  = fmaf(b0, x2, T[2]);
        T[3] = fmaf(b1, x0, T[3]);  T[4] = fmaf(b1, x1, T[4]);  T[5]  = fmaf(b1, x2, T[5]);
        T[6] = fmaf(b2, x0, T[6]);  T[7] = fmaf(b2, x1, T[7]);  T[8]  = fmaf(b2, x2, T[8]);
        T[9] = fmaf(b3, x0, T[9]);  T[10]= fmaf(b3, x1, T[10]); T[11] = fmaf(b3, x2, T[11]);
    }
    float ov[16];
#pragma unroll
    for (int o = 0; o < 16; ++o) {
        float acc = 0.f;
#pragma unroll
        for (int k = 0; k < 4; ++k)
#pragma unroll
            for (int i = 0; i < 3; ++i)
                acc = fmaf(T[k * 3 + i], sW[k * 48 + i * 16 + o], acc);
        acc += __shfl_xor(acc, 1);
        acc += __shfl_xor(acc, 2);
        ov[o] = acc;
    }
    if (sub != 0) return;
    float inv = 1.f / fmaxf((float)(end - off), 1.f);
    __half2 hh[8];
#pragma unroll
    for (int q = 0; q < 8; ++q)
        hh[q] = __float22half2_rn(make_float2(eluf(ov[2 * q] * inv),
                                              eluf(ov[2 * q + 1] * inv)));
    uint4* hp = (uint4*)(h1 + (long)n * 16);
    hp[0] = *(uint4*)&hh[0];
    hp[1] = *(uint4*)&hh[4];
}

// ---- BN1 stats from fp16 h1 ----
__global__ void bn_sum16h(const __half2* __restrict__ h, float* __restrict__ st) {
    __shared__ float ss[16], sq[16];
    if (threadIdx.x < 16) { ss[threadIdx.x] = 0.f; sq[threadIdx.x] = 0.f; }
    __syncthreads();
    const int total = NN * 8;                 // half2 elements
    const int stride = gridDim.x * blockDim.x; // multiple of 8
    float a0 = 0.f, a1 = 0.f, q0 = 0.f, q1 = 0.f;
    for (int i = blockIdx.x * blockDim.x + threadIdx.x; i < total; i += stride) {
        float2 f = __half22float2(h[i]);
        a0 += f.x; q0 += f.x * f.x;
        a1 += f.y; q1 += f.y * f.y;
    }
#pragma unroll
    for (int d = 8; d < 64; d <<= 1) {
        a0 += __shfl_xor(a0, d); q0 += __shfl_xor(q0, d);
        a1 += __shfl_xor(a1, d); q1 += __shfl_xor(q1, d);
    }
    int lane = threadIdx.x & 63;
    if (lane < 8) {
        atomicAdd(&ss[2 * lane], a0);     atomicAdd(&sq[2 * lane], q0);
        atomicAdd(&ss[2 * lane + 1], a1); atomicAdd(&sq[2 * lane + 1], q1);
    }
    __syncthreads();
    if (threadIdx.x < 16) {
        atomAdd(&st[threadIdx.x], ss[threadIdx.x]);
        atomAdd(&st[16 + threadIdx.x], sq[threadIdx.x]);
    }
}

// ---- BN2 stats over f32 h2 ----
__global__ void bn_sum32(const float* __restrict__ h, float* __restrict__ st) {
    __shared__ float ss[32], sq[32];
    if (threadIdx.x < 32) { ss[threadIdx.x] = 0.f; sq[threadIdx.x] = 0.f; }
    __syncthreads();
    const int total = NN * 32;
    const int stride = gridDim.x * blockDim.x;
    float a = 0.f, q = 0.f;
    for (int i = blockIdx.x * blockDim.x + threadIdx.x; i < total; i += stride) {
        float v = h[i];
        a += v; q += v * v;
    }
    a += __shfl_xor(a, 32);
    q += __shfl_xor(q, 32);
    int lane = threadIdx.x & 63;
    if (lane < 32) { atomicAdd(&ss[lane], a); atomicAdd(&sq[lane], q); }
    __syncthreads();
    if (threadIdx.x < 32) {
        atomAdd(&st[threadIdx.x], ss[threadIdx.x]);
        atomAdd(&st[32 + threadIdx.x], sq[threadIdx.x]);
    }
}

// ---- conv2: 8 threads/node = 2 edge-halves x 4 k-slots. Uk[16] per thread,
//      static GEMV vs k-slice of LDS sc*W2, shfl-reduce over sub-lanes.
//      No runtime-indexed arrays -> zero scratch. ----
__global__ void __launch_bounds__(256) conv2_gather(const int* __restrict__ offs,
        const uint2* __restrict__ recs, const __half* __restrict__ h1,
        const float* __restrict__ st1, const float* __restrict__ g1,
        const float* __restrict__ b1v, const float* __restrict__ W2,
        float* __restrict__ h2) {
    __shared__ float s_sc[16], s_sh[16];
    __shared__ float sWp[2048];  // sc_i * W2[k][i][o]
    __shared__ float sV[128];    // sum_i sh_i * W2[k][i][o]
    if (threadIdx.x < 16) {
        int c = threadIdx.x;
        float mu = st1[c] * (1.f / NN);
        float var = st1[16 + c] * (1.f / NN) - mu * mu;
        float rs = rsqrtf(var + EPSF);
        float s = g1[c] * rs;
        s_sc[c] = s;
        s_sh[c] = b1v[c] - mu * s;
    }
    __syncthreads();
    for (int idx = threadIdx.x; idx < 2048; idx += blockDim.x) {
        int i = (idx & 511) >> 5;
        sWp[idx] = s_sc[i] * W2[idx];
    }
    if (threadIdx.x < 128) {
        int k = threadIdx.x >> 5, o = threadIdx.x & 31;
        float acc = 0.f;
#pragma unroll
        for (int i = 0; i < 16; ++i) acc = fmaf(s_sh[i], W2[k * 512 + i * 32 + o], acc);
        sV[threadIdx.x] = acc;
    }
    __syncthreads();
    int t = blockIdx.x * blockDim.x + threadIdx.x;
    int n = t >> 3, sub = t & 7;
    if (n >= NN) return;
    int k = sub & 3, half = sub >> 2;
    int off = offs[n], end = offs[n + 1];
    float Uk[16];
#pragma unroll
    for (int i = 0; i < 16; ++i) Uk[i] = 0.f;
    float Sk = 0.f;
    for (int e = off + half; e < end; e += 2) {
        uint2 r = recs[e];
        int s = (int)(r.x & 0x1FFFFu);
        float p0 = (float)(r.x >> 17) * INV32767;
        float p1 = (float)(r.y >> 17) * INV32767;
        float f0 = (k & 1) ? p0 : 1.f - p0;
        float f1 = (k & 2) ? p1 : 1.f - p1;
        float bk = f0 * f1;
        const uint4* hp = (const uint4*)(h1 + (long)s * 16);
        uint4 ua = hp[0], ub = hp[1];
        float2 f0v = __half22float2(*(const __half2*)&ua.x);
        float2 f1v = __half22float2(*(const __half2*)&ua.y);
        float2 f2v = __half22float2(*(const __half2*)&ua.z);
        float2 f3v = __half22float2(*(const __half2*)&ua.w);
        float2 f4v = __half22float2(*(const __half2*)&ub.x);
        float2 f5v = __half22float2(*(const __half2*)&ub.y);
        float2 f6v = __half22float2(*(const __half2*)&ub.z);
        float2 f7v = __half22float2(*(const __half2*)&ub.w);
        Uk[0]  = fmaf(bk, f0v.x, Uk[0]);  Uk[1]  = fmaf(bk, f0v.y, Uk[1]);
        Uk[2]  = fmaf(bk, f1v.x, Uk[2]);  Uk[3]  = fmaf(bk, f1v.y, Uk[3]);
        Uk[4]  = fmaf(bk, f2v.x, Uk[4]);  Uk[5]  = fmaf(bk, f2v.y, Uk[5]);
        Uk[6]  = fmaf(bk, f3v.x, Uk[6]);  Uk[7]  = fmaf(bk, f3v.y, Uk[7]);
        Uk[8]  = fmaf(bk, f4v.x, Uk[8]);  Uk[9]  = fmaf(bk, f4v.y, Uk[9]);
        Uk[10] = fmaf(bk, f5v.x, Uk[10]); Uk[11] = fmaf(bk, f5v.y, Uk[11]);
        Uk[12] = fmaf(bk, f6v.x, Uk[12]); Uk[13] = fmaf(bk, f6v.y, Uk[13]);
        Uk[14] = fmaf(bk, f7v.x, Uk[14]); Uk[15] = fmaf(bk, f7v.y, Uk[15]);
        Sk += bk;
    }
    float4 acc[8];
    const float4* V4 = (const float4*)(sV + k * 32);
#pragma unroll
    for (int ob = 0; ob < 8; ++ob) {
        float4 v = V4[ob];
        acc[ob] = make_float4(Sk * v.x, Sk * v.y, Sk * v.z, Sk * v.w);
    }
    const float4* Wk4 = (const float4*)(sWp + k * 512);
#pragma unroll
    for (int i = 0; i < 16; ++i) {
        float u = Uk[i];
#pragma unroll
        for (int ob = 0; ob < 8; ++ob) {
            float4 w = Wk4[i * 8 + ob];
            acc[ob].x = fmaf(u, w.x, acc[ob].x);
            acc[ob].y = fmaf(u, w.y, acc[ob].y);
            acc[ob].z = fmaf(u, w.z, acc[ob].z);
            acc[ob].w = fmaf(u, w.w, acc[ob].w);
        }
    }
    // reduce across 8 sub-lanes (xor 1,2 sums k; xor 4 sums halves)
#pragma unroll
    for (int ob = 0; ob < 8; ++ob) {
        acc[ob].x += __shfl_xor(acc[ob].x, 1); acc[ob].y += __shfl_xor(acc[ob].y, 1);
        acc[ob].z += __shfl_xor(acc[ob].z, 1); acc[ob].w += __shfl_xor(acc[ob].w, 1);
        acc[ob].x += __shfl_xor(acc[ob].x, 2); acc[ob].y += __shfl_xor(acc[ob].y, 2);
        acc[ob].z += __shfl_xor(acc[ob].z, 2); acc[ob].w += __shfl_xor(acc[ob].w, 2);
        acc[ob].x += __shfl_xor(acc[ob].x, 4); acc[ob].y += __shfl_xor(acc[ob].y, 4);
        acc[ob].z += __shfl_xor(acc[ob].z, 4); acc[ob].w += __shfl_xor(acc[ob].w, 4);
    }
    if (sub != 0) return;
    float inv = 1.f / fmaxf((float)(end - off), 1.f);
    float4* out4 = (float4*)(h2 + (long)n * 32);
#pragma unroll
    for (int ob = 0; ob < 8; ++ob) {
        float4 a = acc[ob];
        a.x = eluf(a.x * inv); a.y = eluf(a.y * inv);
        a.z = eluf(a.z * inv); a.w = eluf(a.w * inv);
        out4[ob] = a;
    }
}

// ---- per-graph mean pool with BN2 affine, exploiting sorted batch ----
__global__ void pool_k(const float* __restrict__ h2pre, const float* __restrict__ st2,
                       const float* __restrict__ g2, const float* __restrict__ b2v,
                       const int* __restrict__ batch, float* __restrict__ gpool) {
    int t = blockIdx.x * blockDim.x + threadIdx.x;
    int c = t & 31;
    int chunk = t >> 5;
    if (chunk >= NN / 32) return;
    float mu = st2[c] * (1.f / NN);
    float var = st2[32 + c] * (1.f / NN) - mu * mu;
    float rs = rsqrtf(var + EPSF);
    float s = g2[c] * rs;
    float sh = b2v[c] - mu * s;
    int n0 = chunk * 32;
    int g_cur = batch[n0];
    float acc = 0.f;
    for (int i = 0; i < 32; ++i) {
        int n = n0 + i;
        int g = batch[n];
        float v = fmaf(h2pre[(long)n * 32 + c], s, sh);
        if (g != g_cur) {
            atomAdd(gpool + g_cur * 32 + c, acc);
            acc = 0.f;
            g_cur = g;
        }
        acc += v;
    }
    atomAdd(gpool + g_cur * 32 + c, acc);
}

// ---- final: gm = gpool/cnt ; out = gm @ fc^T ----
__global__ void final_k(const float* __restrict__ gpool, const int* __restrict__ starts,
                        const float* __restrict__ fc, float* __restrict__ out) {
    int t = blockIdx.x * blockDim.x + threadIdx.x;
    if (t >= NG * 10) return;
    int g = t / 10, j = t - g * 10;
    float cg = (float)(starts[g + 1] - starts[g]);
    float inv = 1.f / fmaxf(cg, 1.f);
    float sv = 0.f;
#pragma unroll
    for (int ch = 0; ch < 32; ++ch) sv = fmaf(gpool[g * 32 + ch], fc[j * 32 + ch], sv);
    out[t] = sv * inv;
}

extern "C" void kernel_launch(void* const* d_in, const int* in_sizes, int n_in,
                              void* d_out, int out_size, void* d_ws, size_t ws_size,
                              hipStream_t stream) {
    const float* x     = (const float*)d_in[0];
    const int*   ei    = (const int*)d_in[1];
    const float* ea    = (const float*)d_in[2];
    const int*   batch = (const int*)d_in[3];
    const float* W1    = (const float*)d_in[4];
    const float* g1    = (const float*)d_in[5];
    const float* b1v   = (const float*)d_in[6];
    const float* W2    = (const float*)d_in[7];
    const float* g2    = (const float*)d_in[8];
    const float* b2v   = (const float*)d_in[9];
    const float* fc    = (const float*)d_in[10];
    float* ws = (float*)d_ws;

    float*  st1    = ws + OFF_ST1;
    float*  st2    = ws + OFF_ST2;
    float*  gpool  = ws + OFF_GPOOL;
    int*    bcnt   = (int*)(ws + OFF_BCNT);
    int*    bbase  = (int*)(ws + OFF_BBASE);
    int*    bcur   = (int*)(ws + OFF_BCUR);
    int*    offs   = (int*)(ws + OFF_OFFS);
    int*    starts = (int*)(ws + OFF_STARTS);
    __half* h1     = (__half*)(ws + OFF_H1);
    float*  h2     = ws + OFF_H2;
    uint2*  recsA  = (uint2*)(ws + OFF_RECSA);
    uint2*  recsB  = (uint2*)(ws + OFF_RECSB);

    hipMemsetAsync(ws, 0, (size_t)ZERO_FLOATS * sizeof(float), stream);
    starts_k<<<1, 128, 0, stream>>>(batch, starts);

    const int BLK = 256;

    bcount_k<<<391, BLK, 0, stream>>>(ei, bcnt);
    bscan_k<<<1, 512, 0, stream>>>(bcnt, bbase, bcur, offs);
    passA<<<(NE + 4095) / 4096, BLK, 0, stream>>>(ei, ea, bcur, recsA);
    fine_k<<<NB, BLK, 0, stream>>>(bbase, recsA, offs, recsB);
    conv1_gather<<<(NN * 4 + BLK - 1) / BLK, BLK, 0, stream>>>(offs, recsB, x, W1, h1);
    bn_sum16h<<<512, BLK, 0, stream>>>((const __half2*)h1, st1);
    conv2_gather<<<(NN * 8 + BLK - 1) / BLK, BLK, 0, stream>>>(offs, recsB, h1, st1, g1, b1v, W2, h2);
    bn_sum32<<<512, BLK, 0, stream>>>(h2, st2);
    pool_k<<<(NN + BLK - 1) / BLK, BLK, 0, stream>>>(h2, st2, g2, b2v, batch, gpool);
    final_k<<<3, BLK, 0, stream>>>(gpool, starts, fc, (float*)d_out);
}